// Round 1
// baseline (324.079 us; speedup 1.0000x reference)
//
#include <hip/hip_runtime.h>
#include <cstddef>
#include <math.h>

// Problem constants (from reference)
#define N_NODES 16384   // B*A
#define DIN 64
#define HID 128
#define HEADS 4
#define CDIM 128        // per-head channel = HID
#define JDIM 512        // HEADS*CDIM
#define SCALE_F 0.17677669529663687f  // (HID/HEADS)^-0.5 = 1/sqrt(32)
#define MAXD 64         // in-degree <= 63 kNN (within 64-node block) + 1 self loop

// ---------------- small precompute ----------------

// G[l*16 + h*4 + a*2 + b] = sum_c Wq[hC+c,a]*Wk[hC+c,b]
__global__ void prep_G_kernel(const float* __restrict__ Wq0, const float* __restrict__ Wk0,
                              const float* __restrict__ Wq1, const float* __restrict__ Wk1,
                              float* __restrict__ G) {
  int t = threadIdx.x;
  if (t >= 32) return;
  int l = t >> 4, h = (t >> 2) & 3, a = (t >> 1) & 1, b = t & 1;
  const float* Wq = l ? Wq1 : Wq0;
  const float* Wk = l ? Wk1 : Wk0;
  float acc = 0.f;
  for (int c = 0; c < CDIM; c++)
    acc += Wq[(h * CDIM + c) * 2 + a] * Wk[(h * CDIM + c) * 2 + b];
  G[t] = acc;
}

// M[j*D + d], j = h*128+o :  sum_c Wv[(h*128+c)*D + d] * Wo[o*512 + h*128 + c]
__global__ void prep_M_kernel(const float* __restrict__ Wv, const float* __restrict__ Wo,
                              float* __restrict__ M, int D) {
  int idx = blockIdx.x * blockDim.x + threadIdx.x;
  if (idx >= JDIM * D) return;
  int j = idx / D, d = idx - j * D;
  int h = j >> 7, o = j & 127;
  const float* wv = Wv + (size_t)(h * CDIM) * D + d;
  const float* wo = Wo + (size_t)o * JDIM + h * CDIM;
  float acc = 0.f;
  for (int c = 0; c < CDIM; c++)
    acc += wv[(size_t)c * D] * wo[c];
  M[(size_t)j * D + d] = acc;
}

// ---------------- CSR build (dst-indexed) ----------------

__global__ void zero_kernel(int* __restrict__ p, int n) {
  int i = blockIdx.x * blockDim.x + threadIdx.x;
  if (i < n) p[i] = 0;
}

__global__ void count_kernel(const int* __restrict__ dst, int E, int* __restrict__ deg) {
  int e = blockIdx.x * blockDim.x + threadIdx.x;
  if (e < E) atomicAdd(&deg[dst[e]], 1);
}

// single-block exclusive scan over N_NODES=16384 (1024 threads x 16 each)
__global__ __launch_bounds__(1024) void scan_kernel(const int* __restrict__ deg,
                                                    int* __restrict__ rowstart,
                                                    int* __restrict__ wp) {
  __shared__ int part[1024];
  int t = threadIdx.x;
  int local[16];
  int sum = 0;
#pragma unroll
  for (int i = 0; i < 16; i++) { local[i] = deg[t * 16 + i]; sum += local[i]; }
  part[t] = sum;
  __syncthreads();
  for (int off = 1; off < 1024; off <<= 1) {
    int v = 0;
    if (t >= off) v = part[t - off];
    __syncthreads();
    part[t] += v;
    __syncthreads();
  }
  int run = (t > 0) ? part[t - 1] : 0;
#pragma unroll
  for (int i = 0; i < 16; i++) {
    rowstart[t * 16 + i] = run;
    wp[t * 16 + i] = run;
    run += local[i];
  }
  if (t == 1023) rowstart[N_NODES] = run;
}

__global__ void scatter_kernel(const int* __restrict__ src, const int* __restrict__ dst,
                               int E, int* __restrict__ wp, int* __restrict__ csr_src) {
  int e = blockIdx.x * blockDim.x + threadIdx.x;
  if (e < E) {
    int p = atomicAdd(&wp[dst[e]], 1);
    csr_src[p] = src[e];
  }
}

// ---------------- dense GEMM: out[n,j] = act(sum_d in[n,d]*W[j,d] + bias[j]) ----------------
// Requires: Nrows%64==0 (grid.y), J%64==0 (grid.x), D%16==0.
__global__ __launch_bounds__(256) void gemm_kernel(
    const float* __restrict__ in, const float* __restrict__ W,
    const float* __restrict__ bias, float* __restrict__ out,
    int J, int D, int act)
{
  __shared__ __align__(16) float sIn[16][68];  // [k][row], stride 68 -> 16B aligned rows, 2-way banks
  __shared__ __align__(16) float sW[16][68];
  int tid = threadIdx.x;
  int jb = blockIdx.x * 64;
  int rb = blockIdx.y * 64;
  int tx = tid & 15, ty = tid >> 4;
  int lr = tid >> 2;            // 0..63: tile row being loaded
  int lc = (tid & 3) << 2;      // 0,4,8,12: k-offset of float4
  const float* gin = in + (size_t)(rb + lr) * D + lc;
  const float* gw  = W  + (size_t)(jb + lr) * D + lc;
  float acc[4][4] = {};
  for (int k0 = 0; k0 < D; k0 += 16) {
    float4 va = *(const float4*)(gin + k0);
    float4 vb = *(const float4*)(gw + k0);
    __syncthreads();
    sIn[lc + 0][lr] = va.x; sIn[lc + 1][lr] = va.y; sIn[lc + 2][lr] = va.z; sIn[lc + 3][lr] = va.w;
    sW [lc + 0][lr] = vb.x; sW [lc + 1][lr] = vb.y; sW [lc + 2][lr] = vb.z; sW [lc + 3][lr] = vb.w;
    __syncthreads();
#pragma unroll
    for (int kk = 0; kk < 16; kk++) {
      float4 a = *(const float4*)&sIn[kk][ty << 2];
      float4 b = *(const float4*)&sW[kk][tx << 2];
      acc[0][0] += a.x * b.x; acc[0][1] += a.x * b.y; acc[0][2] += a.x * b.z; acc[0][3] += a.x * b.w;
      acc[1][0] += a.y * b.x; acc[1][1] += a.y * b.y; acc[1][2] += a.y * b.z; acc[1][3] += a.y * b.w;
      acc[2][0] += a.z * b.x; acc[2][1] += a.z * b.y; acc[2][2] += a.z * b.z; acc[2][3] += a.z * b.w;
      acc[3][0] += a.w * b.x; acc[3][1] += a.w * b.y; acc[3][2] += a.w * b.z; acc[3][3] += a.w * b.w;
    }
  }
#pragma unroll
  for (int i = 0; i < 4; i++) {
    int r = rb + (ty << 2) + i;
#pragma unroll
    for (int j = 0; j < 4; j++) {
      int c = jb + (tx << 2) + j;
      float v = acc[i][j];
      if (bias) v += bias[c];
      if (act == 1) v = fmaxf(v, 0.f);
      out[(size_t)r * J + c] = v;
    }
  }
}

// ---------------- fused attention: softmax over in-edges + aggregate + bias + tanh ----------------
// out[n,o] = tanh( bo[o] + sum_j sum_h a[j,h] * wph[src_j, h*128+o] ), a = softmax_j over per-node edges
__global__ __launch_bounds__(128) void attn_kernel(
    const int* __restrict__ rowstart, const int* __restrict__ csr_src,
    const float* __restrict__ pos, const float* __restrict__ G,
    const float* __restrict__ wph, const float* __restrict__ bo,
    float* __restrict__ out)
{
  int n = blockIdx.x;
  __shared__ float sA[MAXD][5];  // [edge][head], pad to 5 for bank spread
  __shared__ int sS[MAXD];
  int rs = rowstart[n];
  int deg = rowstart[n + 1] - rs;
  if (deg > MAXD) deg = MAXD;  // structurally impossible, defensive
  int t = threadIdx.x;
  float p0 = pos[2 * n], p1 = pos[2 * n + 1];
  if (t < deg) {
    int s = csr_src[rs + t];
    sS[t] = s;
    float q0 = pos[2 * s], q1 = pos[2 * s + 1];
#pragma unroll
    for (int h = 0; h < HEADS; h++) {
      const float* g = G + h * 4;
      sA[t][h] = (p0 * (g[0] * q0 + g[1] * q1) + p1 * (g[2] * q0 + g[3] * q1)) * SCALE_F;
    }
  }
  __syncthreads();
  if (t < 64) {  // wave 0 does the 4 per-head softmaxes over <=64 edges
#pragma unroll
    for (int h = 0; h < HEADS; h++) {
      float v = (t < deg) ? sA[t][h] : -1e30f;
      for (int off = 32; off >= 1; off >>= 1) v = fmaxf(v, __shfl_xor(v, off));
      float ex = (t < deg) ? __expf(sA[t][h] - v) : 0.f;
      float s = ex;
      for (int off = 32; off >= 1; off >>= 1) s += __shfl_xor(s, off);
      if (t < deg) sA[t][h] = ex / s;
    }
  }
  __syncthreads();
  float acc = bo[t];
  for (int j = 0; j < deg; j++) {
    int s = sS[j];
    const float* w = wph + (size_t)s * JDIM + t;  // coalesced across t
    acc += sA[j][0] * w[0] + sA[j][1] * w[CDIM] + sA[j][2] * w[2 * CDIM] + sA[j][3] * w[3 * CDIM];
  }
  out[(size_t)n * HID + t] = tanhf(acc);
}

// ---------------- final tiny GEMM: out[n,0..1] = in[n,:]@W3.T + b3 ----------------
__global__ __launch_bounds__(256) void final_kernel(const float* __restrict__ in,
                                                    const float* __restrict__ W3,
                                                    const float* __restrict__ b3,
                                                    float* __restrict__ out) {
  int lane = threadIdx.x & 63;
  int nl = threadIdx.x >> 6;
  int n = blockIdx.x * 4 + nl;
  const float* row = in + (size_t)n * 256;
  float s0 = 0.f, s1 = 0.f;
#pragma unroll
  for (int tt = 0; tt < 4; tt++) {
    float xv = row[lane + 64 * tt];
    s0 += xv * W3[lane + 64 * tt];
    s1 += xv * W3[256 + lane + 64 * tt];
  }
  for (int off = 32; off >= 1; off >>= 1) {
    s0 += __shfl_xor(s0, off);
    s1 += __shfl_xor(s1, off);
  }
  if (lane == 0) {
    out[n * 2 + 0] = s0 + b3[0];
    out[n * 2 + 1] = s1 + b3[1];
  }
}

// ---------------- launch ----------------

extern "C" void kernel_launch(void* const* d_in, const int* in_sizes, int n_in,
                              void* d_out, int out_size, void* d_ws, size_t ws_size,
                              hipStream_t stream) {
  const float* x     = (const float*)d_in[0];
  const float* pos   = (const float*)d_in[1];
  const int*   ei    = (const int*)d_in[2];
  const float* l0_Wq = (const float*)d_in[3];
  const float* l0_Wk = (const float*)d_in[4];
  const float* l0_Wv = (const float*)d_in[5];
  const float* l0_Wo = (const float*)d_in[6];
  const float* l0_bo = (const float*)d_in[7];
  const float* l1_Wq = (const float*)d_in[8];
  const float* l1_Wk = (const float*)d_in[9];
  const float* l1_Wv = (const float*)d_in[10];
  const float* l1_Wo = (const float*)d_in[11];
  const float* l1_bo = (const float*)d_in[12];
  const float* W1    = (const float*)d_in[13];
  const float* b1    = (const float*)d_in[14];
  const float* W2    = (const float*)d_in[15];
  const float* b2    = (const float*)d_in[16];
  const float* W3    = (const float*)d_in[17];
  const float* b3    = (const float*)d_in[18];
  float* outp = (float*)d_out;

  int E = in_sizes[2] / 2;
  const int* srcp = ei;
  const int* dstp = ei + E;

  char* base = (char*)d_ws;
  size_t off = 0;
  auto alloc = [&](size_t bytes) -> void* {
    void* p = base + off;
    off = (off + bytes + 255) & ~(size_t)255;
    return p;
  };
  float* G    = (float*)alloc(32 * sizeof(float));
  float* M0   = (float*)alloc((size_t)JDIM * DIN * sizeof(float));
  float* M1   = (float*)alloc((size_t)JDIM * HID * sizeof(float));
  int*   deg  = (int*)alloc((size_t)N_NODES * sizeof(int));
  int*   rowst= (int*)alloc((size_t)(N_NODES + 1) * sizeof(int));
  int*   wp   = (int*)alloc((size_t)N_NODES * sizeof(int));
  int*   csr  = (int*)alloc((size_t)E * sizeof(int));
  float* wph  = (float*)alloc((size_t)N_NODES * JDIM * sizeof(float));  // 33.5 MB, reused
  float* h1   = (float*)alloc((size_t)N_NODES * HID * sizeof(float));
  float* h2   = (float*)alloc((size_t)N_NODES * HID * sizeof(float));
  float* m1 = wph;                                  // reuse wph after attn1
  float* m2 = wph + (size_t)N_NODES * 256;

  // precompute folded weights
  prep_G_kernel<<<1, 64, 0, stream>>>(l0_Wq, l0_Wk, l1_Wq, l1_Wk, G);
  prep_M_kernel<<<(JDIM * DIN + 255) / 256, 256, 0, stream>>>(l0_Wv, l0_Wo, M0, DIN);
  prep_M_kernel<<<(JDIM * HID + 255) / 256, 256, 0, stream>>>(l1_Wv, l1_Wo, M1, HID);

  // CSR build
  zero_kernel<<<(N_NODES + 255) / 256, 256, 0, stream>>>(deg, N_NODES);
  count_kernel<<<(E + 255) / 256, 256, 0, stream>>>(dstp, E, deg);
  scan_kernel<<<1, 1024, 0, stream>>>(deg, rowst, wp);
  scatter_kernel<<<(E + 255) / 256, 256, 0, stream>>>(srcp, dstp, E, wp, csr);

  dim3 g512(JDIM / 64, N_NODES / 64);
  dim3 g256(256 / 64, N_NODES / 64);

  // layer 0
  gemm_kernel<<<g512, 256, 0, stream>>>(x, M0, nullptr, wph, JDIM, DIN, 0);
  attn_kernel<<<N_NODES, 128, 0, stream>>>(rowst, csr, pos, G, wph, l0_bo, h1);
  // layer 1
  gemm_kernel<<<g512, 256, 0, stream>>>(h1, M1, nullptr, wph, JDIM, HID, 0);
  attn_kernel<<<N_NODES, 128, 0, stream>>>(rowst, csr, pos, G + 16, wph, l1_bo, h2);
  // MLP
  gemm_kernel<<<g256, 256, 0, stream>>>(h2, W1, b1, m1, 256, HID, 1);
  gemm_kernel<<<g256, 256, 0, stream>>>(m1, W2, b2, m2, 256, 256, 1);
  final_kernel<<<N_NODES / 4, 256, 0, stream>>>(m2, W3, b3, outp);

  (void)n_in; (void)out_size; (void)ws_size;
}

// Round 2
// 288.203 us; speedup vs baseline: 1.1245x; 1.1245x over previous
//
#include <hip/hip_runtime.h>
#include <cstddef>
#include <math.h>

// Problem constants (from reference)
#define N_NODES 16384   // B*A
#define DIN 64
#define HID 128
#define HEADS 4
#define CDIM 128        // per-head channel = HID
#define JDIM 512        // HEADS*CDIM
#define SCALE_F 0.17677669529663687f  // 1/sqrt(32)

// ---------------- small precompute ----------------

// G[l*16 + h*4 + a*2 + b] = sum_c Wq[hC+c,a]*Wk[hC+c,b]
__global__ void prep_G_kernel(const float* __restrict__ Wq0, const float* __restrict__ Wk0,
                              const float* __restrict__ Wq1, const float* __restrict__ Wk1,
                              float* __restrict__ G) {
  int t = threadIdx.x;
  if (t >= 32) return;
  int l = t >> 4, h = (t >> 2) & 3, a = (t >> 1) & 1, b = t & 1;
  const float* Wq = l ? Wq1 : Wq0;
  const float* Wk = l ? Wk1 : Wk0;
  float acc = 0.f;
  for (int c = 0; c < CDIM; c++)
    acc += Wq[(h * CDIM + c) * 2 + a] * Wk[(h * CDIM + c) * 2 + b];
  G[t] = acc;
}

// Mf[o][h*D+d] = sum_c Wv[(h*128+c)*D + d] * Wo[o*512 + h*128 + c]   (128 x 4D)
__global__ void prep_M_kernel(const float* __restrict__ Wv, const float* __restrict__ Wo,
                              float* __restrict__ Mf, int D) {
  int K4 = 4 * D;
  int idx = blockIdx.x * blockDim.x + threadIdx.x;
  if (idx >= 128 * K4) return;
  int o = idx / K4, hd = idx - o * K4;
  int h = hd / D, d = hd - h * D;
  const float* wv = Wv + (size_t)(h * CDIM) * D + d;
  const float* wo = Wo + (size_t)o * JDIM + h * CDIM;
  float acc = 0.f;
  for (int c = 0; c < CDIM; c++)
    acc += wv[(size_t)c * D] * wo[c];
  Mf[idx] = acc;
}

// ---------------- adjacency bitmask (block-local graph) ----------------

__global__ void zero_kernel(unsigned long long* __restrict__ p, int n) {
  int i = blockIdx.x * blockDim.x + threadIdx.x;
  if (i < n) p[i] = 0ull;
}

__global__ void mask_kernel(const int* __restrict__ src, const int* __restrict__ dst,
                            int E, unsigned long long* __restrict__ mask) {
  int e = blockIdx.x * blockDim.x + threadIdx.x;
  if (e < E) atomicOr(&mask[dst[e]], 1ull << (src[e] & 63));
}

// ---------------- block-local attention + aggregation ----------------
// Per block b (64 nodes): scores s(dst,src,h) = pos_dst^T G_h pos_src * SCALE on edges,
// softmax over src per (dst,h), agg[dst][h*D+d] = sum_src a * X[src][d].
template <int D>
__global__ __launch_bounds__(256) void attn_kernel(
    const float* __restrict__ xin,   // N x D
    const float* __restrict__ pos,   // N x 2
    const unsigned long long* __restrict__ mask,  // N
    const float* __restrict__ G,     // 16 floats (this layer)
    float* __restrict__ agg)         // N x 4D
{
  constexpr int P = D + 4;           // padded row, keeps 16B alignment
  __shared__ float sX[64 * P];
  __shared__ float sA[64][64];       // [src][dst], one head at a time
  __shared__ float sInv[64];
  __shared__ float sPos[128];
  int b = blockIdx.x, t = threadIdx.x;
  if (t < 128) sPos[t] = pos[b * 128 + t];
  const float4* gx = (const float4*)(xin + (size_t)b * 64 * D);
  for (int i = t; i < 16 * D; i += 256) {   // 64*D/4 float4s
    float4 v = gx[i];
    int src = (i * 4) / D, d = (i * 4) - src * D;
    float* p = &sX[src * P + d];
    p[0] = v.x; p[1] = v.y; p[2] = v.z; p[3] = v.w;
  }
  // phase-A role: 4 threads (same wave quad) per dst, 16 src each
  int dstA = t >> 2, q = t & 3;
  unsigned mbits = (unsigned)((mask[b * 64 + dstA] >> (q * 16)) & 0xFFFFu);
  float pd0 = pos[(b * 64 + dstA) * 2], pd1 = pos[(b * 64 + dstA) * 2 + 1];
  // phase-B role: micro-tile 4 dst x 4 d
  int tx = t & 15, ty = t >> 4;
  int dst0 = ty * 4;
  __syncthreads();

  for (int h = 0; h < 4; h++) {
    { // ---- phase A (head h): masked softmax weights into sA ----
      const float* g = G + h * 4;
      float a0 = (g[0] * pd0 + g[2] * pd1) * SCALE_F;
      float a1 = (g[1] * pd0 + g[3] * pd1) * SCALE_F;
      float sc[16];
      float mx = -1e30f;
#pragma unroll
      for (int i = 0; i < 16; i++) {
        int s = q * 16 + i;
        sc[i] = a0 * sPos[2 * s] + a1 * sPos[2 * s + 1];
        if ((mbits >> i) & 1) mx = fmaxf(mx, sc[i]);
      }
      mx = fmaxf(mx, __shfl_xor(mx, 1));
      mx = fmaxf(mx, __shfl_xor(mx, 2));
      float sum = 0.f;
#pragma unroll
      for (int i = 0; i < 16; i++) {
        float ex = ((mbits >> i) & 1) ? __expf(sc[i] - mx) : 0.f;
        sA[q * 16 + i][dstA] = ex;
        sum += ex;
      }
      sum += __shfl_xor(sum, 1);
      sum += __shfl_xor(sum, 2);
      if (q == 0) sInv[dstA] = 1.f / sum;
    }
    __syncthreads();
    { // ---- phase B (head h): agg_tile = A^T-slice @ X ----
#pragma unroll
      for (int dd = 0; dd < D / 64; dd++) {
        int d0 = (dd * 16 + tx) * 4;
        float acc[4][4] = {};
#pragma unroll 16
        for (int s = 0; s < 64; s++) {
          float4 av = *(const float4*)&sA[s][dst0];
          float4 xv = *(const float4*)&sX[s * P + d0];
          acc[0][0] += av.x * xv.x; acc[0][1] += av.x * xv.y; acc[0][2] += av.x * xv.z; acc[0][3] += av.x * xv.w;
          acc[1][0] += av.y * xv.x; acc[1][1] += av.y * xv.y; acc[1][2] += av.y * xv.z; acc[1][3] += av.y * xv.w;
          acc[2][0] += av.z * xv.x; acc[2][1] += av.z * xv.y; acc[2][2] += av.z * xv.z; acc[2][3] += av.z * xv.w;
          acc[3][0] += av.w * xv.x; acc[3][1] += av.w * xv.y; acc[3][2] += av.w * xv.z; acc[3][3] += av.w * xv.w;
        }
#pragma unroll
        for (int i = 0; i < 4; i++) {
          float inv = sInv[dst0 + i];
          size_t n = (size_t)(b * 64 + dst0 + i);
          float4 o4 = make_float4(acc[i][0] * inv, acc[i][1] * inv, acc[i][2] * inv, acc[i][3] * inv);
          *(float4*)&agg[n * (4 * D) + h * D + d0] = o4;
        }
      }
    }
    if (h < 3) __syncthreads();  // protect sA/sInv overwrite
  }
}

// ---------------- dense GEMM: out[n,j] = act(sum_d in[n,d]*W[j,d] + bias[j]) ----------------
// Nrows%64==0, J%64==0, K%32==0. act: 0 none, 1 relu, 2 tanh.
__global__ __launch_bounds__(256) void gemm_kernel(
    const float* __restrict__ in, const float* __restrict__ W,
    const float* __restrict__ bias, float* __restrict__ out,
    int J, int K, int act)
{
  __shared__ __align__(16) float sIn[32][68];
  __shared__ __align__(16) float sW[32][68];
  int tid = threadIdx.x;
  int jb = blockIdx.x * 64;
  int rb = blockIdx.y * 64;
  int tx = tid & 15, ty = tid >> 4;
  int lr = tid >> 2;            // row 0..63
  int lc = (tid & 3) << 2;      // 0,4,8,12
  const float* gin = in + (size_t)(rb + lr) * K + lc;
  const float* gw  = W  + (size_t)(jb + lr) * K + lc;
  float acc[4][4] = {};
  for (int k0 = 0; k0 < K; k0 += 32) {
    float4 va0 = *(const float4*)(gin + k0);
    float4 va1 = *(const float4*)(gin + k0 + 16);
    float4 vb0 = *(const float4*)(gw + k0);
    float4 vb1 = *(const float4*)(gw + k0 + 16);
    __syncthreads();
    sIn[lc + 0][lr] = va0.x; sIn[lc + 1][lr] = va0.y; sIn[lc + 2][lr] = va0.z; sIn[lc + 3][lr] = va0.w;
    sIn[lc + 16][lr] = va1.x; sIn[lc + 17][lr] = va1.y; sIn[lc + 18][lr] = va1.z; sIn[lc + 19][lr] = va1.w;
    sW [lc + 0][lr] = vb0.x; sW [lc + 1][lr] = vb0.y; sW [lc + 2][lr] = vb0.z; sW [lc + 3][lr] = vb0.w;
    sW [lc + 16][lr] = vb1.x; sW [lc + 17][lr] = vb1.y; sW [lc + 18][lr] = vb1.z; sW [lc + 19][lr] = vb1.w;
    __syncthreads();
#pragma unroll
    for (int kk = 0; kk < 32; kk++) {
      float4 a = *(const float4*)&sIn[kk][ty << 2];
      float4 b = *(const float4*)&sW[kk][tx << 2];
      acc[0][0] += a.x * b.x; acc[0][1] += a.x * b.y; acc[0][2] += a.x * b.z; acc[0][3] += a.x * b.w;
      acc[1][0] += a.y * b.x; acc[1][1] += a.y * b.y; acc[1][2] += a.y * b.z; acc[1][3] += a.y * b.w;
      acc[2][0] += a.z * b.x; acc[2][1] += a.z * b.y; acc[2][2] += a.z * b.z; acc[2][3] += a.z * b.w;
      acc[3][0] += a.w * b.x; acc[3][1] += a.w * b.y; acc[3][2] += a.w * b.z; acc[3][3] += a.w * b.w;
    }
  }
#pragma unroll
  for (int i = 0; i < 4; i++) {
    int r = rb + (ty << 2) + i;
#pragma unroll
    for (int j = 0; j < 4; j++) {
      int c = jb + (tx << 2) + j;
      float v = acc[i][j];
      if (bias) v += bias[c];
      if (act == 1) v = fmaxf(v, 0.f);
      else if (act == 2) v = tanhf(v);
      out[(size_t)r * J + c] = v;
    }
  }
}

// ---------------- final tiny GEMM: out[n,0..1] = in[n,:]@W3.T + b3 ----------------
__global__ __launch_bounds__(256) void final_kernel(const float* __restrict__ in,
                                                    const float* __restrict__ W3,
                                                    const float* __restrict__ b3,
                                                    float* __restrict__ out) {
  int lane = threadIdx.x & 63;
  int nl = threadIdx.x >> 6;
  int n = blockIdx.x * 4 + nl;
  const float* row = in + (size_t)n * 256;
  float s0 = 0.f, s1 = 0.f;
#pragma unroll
  for (int tt = 0; tt < 4; tt++) {
    float xv = row[lane + 64 * tt];
    s0 += xv * W3[lane + 64 * tt];
    s1 += xv * W3[256 + lane + 64 * tt];
  }
  for (int off = 32; off >= 1; off >>= 1) {
    s0 += __shfl_xor(s0, off);
    s1 += __shfl_xor(s1, off);
  }
  if (lane == 0) {
    out[n * 2 + 0] = s0 + b3[0];
    out[n * 2 + 1] = s1 + b3[1];
  }
}

// ---------------- launch ----------------

extern "C" void kernel_launch(void* const* d_in, const int* in_sizes, int n_in,
                              void* d_out, int out_size, void* d_ws, size_t ws_size,
                              hipStream_t stream) {
  const float* x     = (const float*)d_in[0];
  const float* pos   = (const float*)d_in[1];
  const int*   ei    = (const int*)d_in[2];
  const float* l0_Wq = (const float*)d_in[3];
  const float* l0_Wk = (const float*)d_in[4];
  const float* l0_Wv = (const float*)d_in[5];
  const float* l0_Wo = (const float*)d_in[6];
  const float* l0_bo = (const float*)d_in[7];
  const float* l1_Wq = (const float*)d_in[8];
  const float* l1_Wk = (const float*)d_in[9];
  const float* l1_Wv = (const float*)d_in[10];
  const float* l1_Wo = (const float*)d_in[11];
  const float* l1_bo = (const float*)d_in[12];
  const float* W1    = (const float*)d_in[13];
  const float* b1    = (const float*)d_in[14];
  const float* W2    = (const float*)d_in[15];
  const float* b2    = (const float*)d_in[16];
  const float* W3    = (const float*)d_in[17];
  const float* b3    = (const float*)d_in[18];
  float* outp = (float*)d_out;

  int E = in_sizes[2] / 2;
  const int* srcp = ei;
  const int* dstp = ei + E;

  char* base = (char*)d_ws;
  size_t off = 0;
  auto alloc = [&](size_t bytes) -> void* {
    void* p = base + off;
    off = (off + bytes + 255) & ~(size_t)255;
    return p;
  };
  float* G   = (float*)alloc(32 * sizeof(float));
  float* Mf0 = (float*)alloc((size_t)128 * 256 * sizeof(float));
  float* Mf1 = (float*)alloc((size_t)128 * 512 * sizeof(float));
  unsigned long long* mask = (unsigned long long*)alloc((size_t)N_NODES * 8);
  float* agg0 = (float*)alloc((size_t)N_NODES * 256 * sizeof(float));  // 16 MB
  float* agg1 = (float*)alloc((size_t)N_NODES * 512 * sizeof(float));  // 33.5 MB
  float* h1   = (float*)alloc((size_t)N_NODES * HID * sizeof(float));
  float* h2   = (float*)alloc((size_t)N_NODES * HID * sizeof(float));
  float* m1 = agg0;   // dead after gemm l0
  float* m2 = agg1;   // dead after gemm l1

  // folded weights
  prep_G_kernel<<<1, 64, 0, stream>>>(l0_Wq, l0_Wk, l1_Wq, l1_Wk, G);
  prep_M_kernel<<<(128 * 256 + 255) / 256, 256, 0, stream>>>(l0_Wv, l0_Wo, Mf0, DIN);
  prep_M_kernel<<<(128 * 512 + 255) / 256, 256, 0, stream>>>(l1_Wv, l1_Wo, Mf1, HID);

  // adjacency bitmask
  zero_kernel<<<(N_NODES + 255) / 256, 256, 0, stream>>>(mask, N_NODES);
  mask_kernel<<<(E + 255) / 256, 256, 0, stream>>>(srcp, dstp, E, mask);

  // layer 0: aggregate in x-space, then folded GEMM + bias + tanh
  attn_kernel<DIN><<<256, 256, 0, stream>>>(x, pos, mask, G, agg0);
  gemm_kernel<<<dim3(2, 256), 256, 0, stream>>>(agg0, Mf0, l0_bo, h1, 128, 256, 2);
  // layer 1
  attn_kernel<HID><<<256, 256, 0, stream>>>(h1, pos, mask, G + 16, agg1);
  gemm_kernel<<<dim3(2, 256), 256, 0, stream>>>(agg1, Mf1, l1_bo, h2, 128, 512, 2);
  // MLP
  gemm_kernel<<<dim3(4, 256), 256, 0, stream>>>(h2, W1, b1, m1, 256, 128, 1);
  gemm_kernel<<<dim3(4, 256), 256, 0, stream>>>(m1, W2, b2, m2, 256, 256, 1);
  final_kernel<<<N_NODES / 4, 256, 0, stream>>>(m2, W3, b3, outp);

  (void)n_in; (void)out_size; (void)ws_size;
}

// Round 3
// 276.283 us; speedup vs baseline: 1.1730x; 1.0431x over previous
//
#include <hip/hip_runtime.h>
#include <hip/hip_bf16.h>
#include <cstddef>
#include <math.h>

// Problem constants (from reference)
#define N_NODES 16384   // B*A
#define DIN 64
#define HID 128
#define HEADS 4
#define CDIM 128        // per-head channel = HID
#define JDIM 512        // HEADS*CDIM
#define SCALE_F 0.17677669529663687f  // 1/sqrt(32)

using bf16x8 = __attribute__((ext_vector_type(8))) short;   // 8 bf16 = 4 VGPRs
using f32x4  = __attribute__((ext_vector_type(4))) float;   // MFMA acc

// fp32 -> bf16 hi + bf16 lo (residual). a ~= hi + lo with |err| <~ 2^-18 |a|.
__device__ inline void split1(float x, ushort& h, ushort& l) {
  __hip_bfloat16 hb = __float2bfloat16(x);
  float r = x - __bfloat162float(hb);
  __hip_bfloat16 lb = __float2bfloat16(r);
  h = *(ushort*)&hb;
  l = *(ushort*)&lb;
}

// ---------------- small precompute ----------------

// G[l*16 + h*4 + a*2 + b] = sum_c Wq[hC+c,a]*Wk[hC+c,b]
__global__ void prep_G_kernel(const float* __restrict__ Wq0, const float* __restrict__ Wk0,
                              const float* __restrict__ Wq1, const float* __restrict__ Wk1,
                              float* __restrict__ G) {
  int t = threadIdx.x;
  if (t >= 32) return;
  int l = t >> 4, h = (t >> 2) & 3, a = (t >> 1) & 1, b = t & 1;
  const float* Wq = l ? Wq1 : Wq0;
  const float* Wk = l ? Wk1 : Wk0;
  float acc = 0.f;
  for (int c = 0; c < CDIM; c++)
    acc += Wq[(h * CDIM + c) * 2 + a] * Wk[(h * CDIM + c) * 2 + b];
  G[t] = acc;
}

// Mf[o][h*D+d] = sum_c Wv[(h*128+c)*D + d] * Wo[o*512 + h*128 + c]   (128 x 4D), split bf16
__global__ void prep_M_kernel(const float* __restrict__ Wv, const float* __restrict__ Wo,
                              ushort* __restrict__ Mhi, ushort* __restrict__ Mlo, int D) {
  int K4 = 4 * D;
  int idx = blockIdx.x * blockDim.x + threadIdx.x;
  if (idx >= 128 * K4) return;
  int o = idx / K4, hd = idx - o * K4;
  int h = hd / D, d = hd - h * D;
  const float* wv = Wv + (size_t)(h * CDIM) * D + d;
  const float* wo = Wo + (size_t)o * JDIM + h * CDIM;
  float acc = 0.f;
  for (int c = 0; c < CDIM; c++)
    acc += wv[(size_t)c * D] * wo[c];
  split1(acc, Mhi[idx], Mlo[idx]);
}

// straight fp32 -> split-bf16 for W1/W2
__global__ void split_kernel(const float* __restrict__ W, ushort* __restrict__ hi,
                             ushort* __restrict__ lo, int n) {
  int i = blockIdx.x * blockDim.x + threadIdx.x;
  if (i < n) split1(W[i], hi[i], lo[i]);
}

// ---------------- adjacency bitmask (block-local graph) ----------------

__global__ void zero_kernel(unsigned long long* __restrict__ p, int n) {
  int i = blockIdx.x * blockDim.x + threadIdx.x;
  if (i < n) p[i] = 0ull;
}

__global__ void mask_kernel(const int* __restrict__ src, const int* __restrict__ dst,
                            int E, unsigned long long* __restrict__ mask) {
  int e = blockIdx.x * blockDim.x + threadIdx.x;
  if (e < E) atomicOr(&mask[dst[e]], 1ull << (src[e] & 63));
}

// ---------------- block-local attention + aggregation (fp32 vector) ----------------
template <int D>
__global__ __launch_bounds__(256) void attn_kernel(
    const float* __restrict__ xin,   // N x D
    const float* __restrict__ pos,   // N x 2
    const unsigned long long* __restrict__ mask,  // N
    const float* __restrict__ G,     // 16 floats (this layer)
    float* __restrict__ agg)         // N x 4D
{
  constexpr int P = D + 4;           // padded row, keeps 16B alignment
  __shared__ float sX[64 * P];
  __shared__ float sA[64][64];       // [src][dst], one head at a time
  __shared__ float sInv[64];
  __shared__ float sPos[128];
  int b = blockIdx.x, t = threadIdx.x;
  if (t < 128) sPos[t] = pos[b * 128 + t];
  const float4* gx = (const float4*)(xin + (size_t)b * 64 * D);
  for (int i = t; i < 16 * D; i += 256) {   // 64*D/4 float4s
    float4 v = gx[i];
    int src = (i * 4) / D, d = (i * 4) - src * D;
    float* p = &sX[src * P + d];
    p[0] = v.x; p[1] = v.y; p[2] = v.z; p[3] = v.w;
  }
  int dstA = t >> 2, q = t & 3;
  unsigned mbits = (unsigned)((mask[b * 64 + dstA] >> (q * 16)) & 0xFFFFu);
  float pd0 = pos[(b * 64 + dstA) * 2], pd1 = pos[(b * 64 + dstA) * 2 + 1];
  int tx = t & 15, ty = t >> 4;
  int dst0 = ty * 4;
  __syncthreads();

  for (int h = 0; h < 4; h++) {
    { // ---- phase A (head h): masked softmax weights into sA ----
      const float* g = G + h * 4;
      float a0 = (g[0] * pd0 + g[2] * pd1) * SCALE_F;
      float a1 = (g[1] * pd0 + g[3] * pd1) * SCALE_F;
      float sc[16];
      float mx = -1e30f;
#pragma unroll
      for (int i = 0; i < 16; i++) {
        int s = q * 16 + i;
        sc[i] = a0 * sPos[2 * s] + a1 * sPos[2 * s + 1];
        if ((mbits >> i) & 1) mx = fmaxf(mx, sc[i]);
      }
      mx = fmaxf(mx, __shfl_xor(mx, 1));
      mx = fmaxf(mx, __shfl_xor(mx, 2));
      float sum = 0.f;
#pragma unroll
      for (int i = 0; i < 16; i++) {
        float ex = ((mbits >> i) & 1) ? __expf(sc[i] - mx) : 0.f;
        sA[q * 16 + i][dstA] = ex;
        sum += ex;
      }
      sum += __shfl_xor(sum, 1);
      sum += __shfl_xor(sum, 2);
      if (q == 0) sInv[dstA] = 1.f / sum;
    }
    __syncthreads();
    { // ---- phase B (head h): agg_tile = A^T-slice @ X ----
#pragma unroll
      for (int dd = 0; dd < D / 64; dd++) {
        int d0 = (dd * 16 + tx) * 4;
        float acc[4][4] = {};
#pragma unroll 16
        for (int s = 0; s < 64; s++) {
          float4 av = *(const float4*)&sA[s][dst0];
          float4 xv = *(const float4*)&sX[s * P + d0];
          acc[0][0] += av.x * xv.x; acc[0][1] += av.x * xv.y; acc[0][2] += av.x * xv.z; acc[0][3] += av.x * xv.w;
          acc[1][0] += av.y * xv.x; acc[1][1] += av.y * xv.y; acc[1][2] += av.y * xv.z; acc[1][3] += av.y * xv.w;
          acc[2][0] += av.z * xv.x; acc[2][1] += av.z * xv.y; acc[2][2] += av.z * xv.z; acc[2][3] += av.z * xv.w;
          acc[3][0] += av.w * xv.x; acc[3][1] += av.w * xv.y; acc[3][2] += av.w * xv.z; acc[3][3] += av.w * xv.w;
        }
#pragma unroll
        for (int i = 0; i < 4; i++) {
          float inv = sInv[dst0 + i];
          size_t n = (size_t)(b * 64 + dst0 + i);
          float4 o4 = make_float4(acc[i][0] * inv, acc[i][1] * inv, acc[i][2] * inv, acc[i][3] * inv);
          *(float4*)&agg[n * (4 * D) + h * D + d0] = o4;
        }
      }
    }
    if (h < 3) __syncthreads();  // protect sA/sInv overwrite
  }
}

// ---------------- split-bf16 MFMA GEMM ----------------
// out[M x J] = act(in[M x K] @ W[J x K]^T + bias), W pre-split into hi/lo bf16.
// Tile: 64(M) x 64(J), K-step 64. Grid: (J/64, M/64). 256 threads (4 waves),
// wave w computes rows w*16..w*16+15, all 64 cols (4 col-tiles of 16).
// a*b ~= ah*bh + ah*bl + al*bh  (error ~2^-18, fp32 accum in MFMA).
#define PITCH 72   // ushort elems/row: 64 + 8 pad -> 144B pitch (16B aligned, 2-way banks = free)

__global__ __launch_bounds__(256) void mgemm_kernel(
    const float* __restrict__ in, const ushort* __restrict__ Whi,
    const ushort* __restrict__ Wlo, const float* __restrict__ bias,
    float* __restrict__ out, int J, int K, int act)
{
  __shared__ ushort sAhi[64 * PITCH];
  __shared__ ushort sAlo[64 * PITCH];
  __shared__ ushort sWhi[64 * PITCH];
  __shared__ ushort sWlo[64 * PITCH];
  int t = threadIdx.x;
  int jb = blockIdx.x * 64;
  int rb = blockIdx.y * 64;
  int wave = t >> 6, lane = t & 63;
  int lm = lane & 15, lq = lane >> 4;
  int arow = wave * 16 + lm;
  f32x4 acc[4];
#pragma unroll
  for (int ct = 0; ct < 4; ct++) acc[ct] = (f32x4){0.f, 0.f, 0.f, 0.f};

  const int Kq = K >> 2, K8 = K >> 3;
  for (int k0 = 0; k0 < K; k0 += 64) {
    // ---- global loads (A fp32, W pre-split bf16) ----
    float4 av[4];
    const float4* gA = (const float4*)(in + (size_t)rb * K + k0);
#pragma unroll
    for (int i = 0; i < 4; i++) {
      int idx = t + i * 256;
      int r = idx >> 4, kq = idx & 15;
      av[i] = gA[(size_t)r * Kq + kq];
    }
    uint4 wh[2], wl[2];
    const uint4* gH = (const uint4*)(Whi + (size_t)jb * K + k0);
    const uint4* gL = (const uint4*)(Wlo + (size_t)jb * K + k0);
#pragma unroll
    for (int i = 0; i < 2; i++) {
      int idx = t + i * 256;
      int r = idx >> 3, kg = idx & 7;
      wh[i] = gH[(size_t)r * K8 + kg];
      wl[i] = gL[(size_t)r * K8 + kg];
    }
    __syncthreads();   // previous iteration's frag reads done
    // ---- LDS stores (A split on the fly) ----
#pragma unroll
    for (int i = 0; i < 4; i++) {
      int idx = t + i * 256;
      int r = idx >> 4, kq = (idx & 15) << 2;
      float4 v = av[i];
      ushort4 h, l;
      split1(v.x, h.x, l.x); split1(v.y, h.y, l.y);
      split1(v.z, h.z, l.z); split1(v.w, h.w, l.w);
      *(ushort4*)&sAhi[r * PITCH + kq] = h;
      *(ushort4*)&sAlo[r * PITCH + kq] = l;
    }
#pragma unroll
    for (int i = 0; i < 2; i++) {
      int idx = t + i * 256;
      int r = idx >> 3, kg = (idx & 7) << 3;
      *(uint4*)&sWhi[r * PITCH + kg] = wh[i];
      *(uint4*)&sWlo[r * PITCH + kg] = wl[i];
    }
    __syncthreads();
    // ---- fragments + MFMA ----
#pragma unroll
    for (int kf = 0; kf < 2; kf++) {
      int ko = kf * 32 + lq * 8;
      bf16x8 ah = *(const bf16x8*)&sAhi[arow * PITCH + ko];
      bf16x8 al = *(const bf16x8*)&sAlo[arow * PITCH + ko];
#pragma unroll
      for (int ct = 0; ct < 4; ct++) {
        bf16x8 bh = *(const bf16x8*)&sWhi[(ct * 16 + lm) * PITCH + ko];
        bf16x8 bl = *(const bf16x8*)&sWlo[(ct * 16 + lm) * PITCH + ko];
        acc[ct] = __builtin_amdgcn_mfma_f32_16x16x32_bf16(ah, bh, acc[ct], 0, 0, 0);
        acc[ct] = __builtin_amdgcn_mfma_f32_16x16x32_bf16(ah, bl, acc[ct], 0, 0, 0);
        acc[ct] = __builtin_amdgcn_mfma_f32_16x16x32_bf16(al, bh, acc[ct], 0, 0, 0);
      }
    }
  }
  // ---- epilogue: C/D layout col=lane&15, row=(lane>>4)*4+reg ----
  int r0 = rb + wave * 16 + lq * 4;
#pragma unroll
  for (int ct = 0; ct < 4; ct++) {
    int c = jb + ct * 16 + lm;
    float bv = bias[c];
#pragma unroll
    for (int rg = 0; rg < 4; rg++) {
      float v = acc[ct][rg] + bv;
      if (act == 1) v = fmaxf(v, 0.f);
      else if (act == 2) v = tanhf(v);
      out[(size_t)(r0 + rg) * J + c] = v;
    }
  }
}

// ---------------- final tiny GEMM: out[n,0..1] = in[n,:]@W3.T + b3 ----------------
__global__ __launch_bounds__(256) void final_kernel(const float* __restrict__ in,
                                                    const float* __restrict__ W3,
                                                    const float* __restrict__ b3,
                                                    float* __restrict__ out) {
  int lane = threadIdx.x & 63;
  int nl = threadIdx.x >> 6;
  int n = blockIdx.x * 4 + nl;
  const float* row = in + (size_t)n * 256;
  float s0 = 0.f, s1 = 0.f;
#pragma unroll
  for (int tt = 0; tt < 4; tt++) {
    float xv = row[lane + 64 * tt];
    s0 += xv * W3[lane + 64 * tt];
    s1 += xv * W3[256 + lane + 64 * tt];
  }
  for (int off = 32; off >= 1; off >>= 1) {
    s0 += __shfl_xor(s0, off);
    s1 += __shfl_xor(s1, off);
  }
  if (lane == 0) {
    out[n * 2 + 0] = s0 + b3[0];
    out[n * 2 + 1] = s1 + b3[1];
  }
}

// ---------------- launch ----------------

extern "C" void kernel_launch(void* const* d_in, const int* in_sizes, int n_in,
                              void* d_out, int out_size, void* d_ws, size_t ws_size,
                              hipStream_t stream) {
  const float* x     = (const float*)d_in[0];
  const float* pos   = (const float*)d_in[1];
  const int*   ei    = (const int*)d_in[2];
  const float* l0_Wq = (const float*)d_in[3];
  const float* l0_Wk = (const float*)d_in[4];
  const float* l0_Wv = (const float*)d_in[5];
  const float* l0_Wo = (const float*)d_in[6];
  const float* l0_bo = (const float*)d_in[7];
  const float* l1_Wq = (const float*)d_in[8];
  const float* l1_Wk = (const float*)d_in[9];
  const float* l1_Wv = (const float*)d_in[10];
  const float* l1_Wo = (const float*)d_in[11];
  const float* l1_bo = (const float*)d_in[12];
  const float* W1    = (const float*)d_in[13];
  const float* b1    = (const float*)d_in[14];
  const float* W2    = (const float*)d_in[15];
  const float* b2    = (const float*)d_in[16];
  const float* W3    = (const float*)d_in[17];
  const float* b3    = (const float*)d_in[18];
  float* outp = (float*)d_out;

  int E = in_sizes[2] / 2;
  const int* srcp = ei;
  const int* dstp = ei + E;

  char* base = (char*)d_ws;
  size_t off = 0;
  auto alloc = [&](size_t bytes) -> void* {
    void* p = base + off;
    off = (off + bytes + 255) & ~(size_t)255;
    return p;
  };
  float*  G     = (float*)alloc(32 * sizeof(float));
  ushort* Mf0hi = (ushort*)alloc((size_t)128 * 256 * 2);
  ushort* Mf0lo = (ushort*)alloc((size_t)128 * 256 * 2);
  ushort* Mf1hi = (ushort*)alloc((size_t)128 * 512 * 2);
  ushort* Mf1lo = (ushort*)alloc((size_t)128 * 512 * 2);
  ushort* W1hi  = (ushort*)alloc((size_t)256 * 128 * 2);
  ushort* W1lo  = (ushort*)alloc((size_t)256 * 128 * 2);
  ushort* W2hi  = (ushort*)alloc((size_t)256 * 256 * 2);
  ushort* W2lo  = (ushort*)alloc((size_t)256 * 256 * 2);
  unsigned long long* mask = (unsigned long long*)alloc((size_t)N_NODES * 8);
  float* agg0 = (float*)alloc((size_t)N_NODES * 256 * sizeof(float));  // 16 MB
  float* agg1 = (float*)alloc((size_t)N_NODES * 512 * sizeof(float));  // 33.5 MB
  float* h1   = (float*)alloc((size_t)N_NODES * HID * sizeof(float));
  float* h2   = (float*)alloc((size_t)N_NODES * HID * sizeof(float));
  float* m1 = agg0;   // dead after mgemm l0
  float* m2 = agg1;   // dead after mgemm l1

  // folded / split weights
  prep_G_kernel<<<1, 64, 0, stream>>>(l0_Wq, l0_Wk, l1_Wq, l1_Wk, G);
  prep_M_kernel<<<(128 * 256 + 255) / 256, 256, 0, stream>>>(l0_Wv, l0_Wo, Mf0hi, Mf0lo, DIN);
  prep_M_kernel<<<(128 * 512 + 255) / 256, 256, 0, stream>>>(l1_Wv, l1_Wo, Mf1hi, Mf1lo, HID);
  split_kernel<<<(256 * 128 + 255) / 256, 256, 0, stream>>>(W1, W1hi, W1lo, 256 * 128);
  split_kernel<<<(256 * 256 + 255) / 256, 256, 0, stream>>>(W2, W2hi, W2lo, 256 * 256);

  // adjacency bitmask
  zero_kernel<<<(N_NODES + 255) / 256, 256, 0, stream>>>(mask, N_NODES);
  mask_kernel<<<(E + 255) / 256, 256, 0, stream>>>(srcp, dstp, E, mask);

  // layer 0: aggregate in x-space, then folded GEMM + bias + tanh
  attn_kernel<DIN><<<256, 256, 0, stream>>>(x, pos, mask, G, agg0);
  mgemm_kernel<<<dim3(2, 256), 256, 0, stream>>>(agg0, Mf0hi, Mf0lo, l0_bo, h1, 128, 256, 2);
  // layer 1
  attn_kernel<HID><<<256, 256, 0, stream>>>(h1, pos, mask, G + 16, agg1);
  mgemm_kernel<<<dim3(2, 256), 256, 0, stream>>>(agg1, Mf1hi, Mf1lo, l1_bo, h2, 128, 512, 2);
  // MLP
  mgemm_kernel<<<dim3(4, 256), 256, 0, stream>>>(h2, W1hi, W1lo, b1, m1, 256, 128, 1);
  mgemm_kernel<<<dim3(4, 256), 256, 0, stream>>>(m1, W2hi, W2lo, b2, m2, 256, 256, 1);
  final_kernel<<<N_NODES / 4, 256, 0, stream>>>(m2, W3, b3, outp);

  (void)n_in; (void)out_size; (void)ws_size;
}

// Round 5
// 258.907 us; speedup vs baseline: 1.2517x; 1.0671x over previous
//
#include <hip/hip_runtime.h>
#include <hip/hip_bf16.h>
#include <cstddef>
#include <math.h>

// Problem constants (from reference)
#define N_NODES 16384   // B*A
#define DIN 64
#define HID 128
#define SCALE_F 0.17677669529663687f  // 1/sqrt(32)

using bf16x8 = __attribute__((ext_vector_type(8))) short;   // 8 bf16 = 4 VGPRs
using f32x4  = __attribute__((ext_vector_type(4))) float;   // MFMA acc

__device__ __forceinline__ ushort f2b(float x) {
  __hip_bfloat16 h = __float2bfloat16(x);
  return *(ushort*)&h;
}
__device__ __forceinline__ float b2f(ushort u) {
  __hip_bfloat16 h = *(__hip_bfloat16*)&u;
  return __bfloat162float(h);
}
// fp32 -> 2-way split (hi+lo), err ~2^-18 |x|  (MLP path, round-3 proven)
__device__ __forceinline__ void split1(float x, ushort& h, ushort& l) {
  h = f2b(x);
  l = f2b(x - b2f(h));
}
// fp32 -> 3-way split (a+b+c), err ~2^-27 |x|  (GAT path)
__device__ __forceinline__ void split3(float x, ushort& a, ushort& b, ushort& c) {
  a = f2b(x);
  float r1 = x - b2f(a);
  b = f2b(r1);
  c = f2b(r1 - b2f(b));
}

// 6-term triple-split product accumulate: acc += (A1+A2+A3)*(B1+B2+B3), dropping <=2^-27 terms
#define MFMA6(acc, A1, A2, A3, B1, B2, B3)                                \
  do {                                                                    \
    acc = __builtin_amdgcn_mfma_f32_16x16x32_bf16(A1, B1, acc, 0, 0, 0);  \
    acc = __builtin_amdgcn_mfma_f32_16x16x32_bf16(A1, B2, acc, 0, 0, 0);  \
    acc = __builtin_amdgcn_mfma_f32_16x16x32_bf16(A2, B1, acc, 0, 0, 0);  \
    acc = __builtin_amdgcn_mfma_f32_16x16x32_bf16(A1, B3, acc, 0, 0, 0);  \
    acc = __builtin_amdgcn_mfma_f32_16x16x32_bf16(A3, B1, acc, 0, 0, 0);  \
    acc = __builtin_amdgcn_mfma_f32_16x16x32_bf16(A2, B2, acc, 0, 0, 0);  \
  } while (0)

// ---------------- small precompute ----------------

// G[l*16 + h*4 + a*2 + b] = sum_c Wq[hC+c,a]*Wk[hC+c,b]
__global__ void prep_G_kernel(const float* __restrict__ Wq0, const float* __restrict__ Wk0,
                              const float* __restrict__ Wq1, const float* __restrict__ Wk1,
                              float* __restrict__ G) {
  int t = threadIdx.x;
  if (t >= 32) return;
  int l = t >> 4, h = (t >> 2) & 3, a = (t >> 1) & 1, b = t & 1;
  const float* Wq = l ? Wq1 : Wq0;
  const float* Wk = l ? Wk1 : Wk0;
  float acc = 0.f;
  for (int c = 0; c < 128; c++)
    acc += Wq[(h * 128 + c) * 2 + a] * Wk[(h * 128 + c) * 2 + b];
  G[t] = acc;
}

// Mf[o][h*D+d] = sum_c Wv[(h*128+c)*D + d] * Wo[o*512 + h*128 + c]   (128 x 4D), triple-split bf16
__global__ void prep_M_kernel(const float* __restrict__ Wv, const float* __restrict__ Wo,
                              ushort* __restrict__ M1, ushort* __restrict__ M2,
                              ushort* __restrict__ M3, int D) {
  int K4 = 4 * D;
  int idx = blockIdx.x * blockDim.x + threadIdx.x;
  if (idx >= 128 * K4) return;
  int o = idx / K4, hd = idx - o * K4;
  int h = hd / D, d = hd - h * D;
  const float* wv = Wv + (size_t)(h * 128) * D + d;
  const float* wo = Wo + (size_t)o * 512 + h * 128;
  float acc = 0.f;
  for (int c = 0; c < 128; c++)
    acc += wv[(size_t)c * D] * wo[c];
  split3(acc, M1[idx], M2[idx], M3[idx]);
}

// split W1 (256x128) and W2 (256x256) in one launch (2-way, MLP path)
__global__ void splitW_kernel(const float* __restrict__ W1, ushort* __restrict__ W1hi,
                              ushort* __restrict__ W1lo, const float* __restrict__ W2,
                              ushort* __restrict__ W2hi, ushort* __restrict__ W2lo) {
  int i = blockIdx.x * blockDim.x + threadIdx.x;
  if (i < 256 * 128) split1(W1[i], W1hi[i], W1lo[i]);
  int j = i - 256 * 128;
  if (j >= 0 && j < 256 * 256) split1(W2[j], W2hi[j], W2lo[j]);
}

// ---------------- adjacency bitmask (block-local graph) ----------------

__global__ void zero_kernel(unsigned long long* __restrict__ p, int n) {
  int i = blockIdx.x * blockDim.x + threadIdx.x;
  if (i < n) p[i] = 0ull;
}

__global__ void mask_kernel(const int* __restrict__ src, const int* __restrict__ dst,
                            int E, unsigned long long* __restrict__ mask) {
  int e = blockIdx.x * blockDim.x + threadIdx.x;
  if (e < E) atomicOr(&mask[dst[e]], 1ull << (src[e] & 63));
}

// ---------------- fused 2-layer GAT (block-local, triple-split MFMA) ----------------
// One workgroup (512 thr) per 64-node block. Per layer, per head h:
//   Y_h = F @ M_h^T   (F fp32 in LDS, split3 to regs once/wave; M pre-split3 from global)
//   h  += A_h @ Y_h   (A split3 in regs; Y split3 at transpose-store into 3 bf16 LDS planes)
// All products are 6-term (err ~2^-27) with fp32 MFMA accumulate.

#define PFW 132   // sF fp32 pitch (floats): 128 + 4 pad, 16B-aligned rows
#define PYW 72    // sY bf16 pitch (ushorts): 64 + 8 pad, 16B-aligned rows

template <int KD>
__device__ __forceinline__ void gat_layer(
    int wave, int lm, int lq,
    const float* sF, ushort* sY1, ushort* sY2, ushort* sY3,
    const float* px, const float* py,
    unsigned mb0, unsigned mb1, float pd0, float pd1,
    const float* __restrict__ G,
    const ushort* __restrict__ M1, const ushort* __restrict__ M2,
    const ushort* __restrict__ M3,
    f32x4 hacc[4])
{
  const int mt = wave & 3;             // dst/src row tile (16 rows)
  const int ntb = (wave >> 2) * 2;     // local o col-tile base (0 or 2)
  const int K4 = 4 * KD;
  const int arow = mt * 16 + lm;

  // F-fragments: load fp32 from LDS, triple-split once per layer
  bf16x8 Fa[KD / 32], Fb[KD / 32], Fc[KD / 32];
#pragma unroll
  for (int kf = 0; kf < KD / 32; kf++) {
    const float* fp = &sF[arow * PFW + kf * 32 + lq * 8];
#pragma unroll
    for (int j = 0; j < 8; j++) {
      ushort a, b, c;
      split3(fp[j], a, b, c);
      Fa[kf][j] = (short)a; Fb[kf][j] = (short)b; Fc[kf][j] = (short)c;
    }
  }
#pragma unroll
  for (int i = 0; i < 4; i++) hacc[i] = (f32x4){0.f, 0.f, 0.f, 0.f};

#pragma unroll
  for (int h = 0; h < 4; h++) {
    // ---- attention A-fragments (A-layout: A[m=lm][k=lq*8+j]), triple-split ----
    float g0 = G[h * 4], g1 = G[h * 4 + 1], g2 = G[h * 4 + 2], g3 = G[h * 4 + 3];
    float a0 = (g0 * pd0 + g2 * pd1) * SCALE_F;
    float a1 = (g1 * pd0 + g3 * pd1) * SCALE_F;
    float s0[8], s1[8];
    float mx = -1e30f;
#pragma unroll
    for (int j = 0; j < 8; j++) {
      int u0 = 8 * lq + j, u1 = 32 + 8 * lq + j;
      s0[j] = a0 * px[u0] + a1 * py[u0];
      s1[j] = a0 * px[u1] + a1 * py[u1];
      if ((mb0 >> j) & 1) mx = fmaxf(mx, s0[j]);
      if ((mb1 >> j) & 1) mx = fmaxf(mx, s1[j]);
    }
    mx = fmaxf(mx, __shfl_xor(mx, 16));
    mx = fmaxf(mx, __shfl_xor(mx, 32));
    float e0[8], e1[8], sum = 0.f;
#pragma unroll
    for (int j = 0; j < 8; j++) {
      e0[j] = ((mb0 >> j) & 1) ? __expf(s0[j] - mx) : 0.f;
      e1[j] = ((mb1 >> j) & 1) ? __expf(s1[j] - mx) : 0.f;
      sum += e0[j] + e1[j];
    }
    sum += __shfl_xor(sum, 16);
    sum += __shfl_xor(sum, 32);
    float inv = 1.f / sum;
    bf16x8 Aa[2], Ab[2], Ac[2];
#pragma unroll
    for (int j = 0; j < 8; j++) {
      ushort a, b, c;
      split3(e0[j] * inv, a, b, c);
      Aa[0][j] = (short)a; Ab[0][j] = (short)b; Ac[0][j] = (short)c;
      split3(e1[j] * inv, a, b, c);
      Aa[1][j] = (short)a; Ab[1][j] = (short)b; Ac[1][j] = (short)c;
    }

    // ---- o in two halves of 64 ----
#pragma unroll
    for (int half = 0; half < 2; half++) {
      // Y_h = F @ M_h^T  (rows=src, cols=o-half)
      f32x4 y[2] = {{0.f, 0.f, 0.f, 0.f}, {0.f, 0.f, 0.f, 0.f}};
#pragma unroll
      for (int kf = 0; kf < KD / 32; kf++) {
#pragma unroll
        for (int i = 0; i < 2; i++) {
          int o = half * 64 + (ntb + i) * 16 + lm;
          size_t boff = (size_t)o * K4 + h * KD + kf * 32 + lq * 8;
          bf16x8 m1 = *(const bf16x8*)&M1[boff];
          bf16x8 m2 = *(const bf16x8*)&M2[boff];
          bf16x8 m3 = *(const bf16x8*)&M3[boff];
          MFMA6(y[i], Fa[kf], Fb[kf], Fc[kf], m1, m2, m3);
        }
      }
      __syncthreads();   // previous half/head A@Y reads of sY complete
      // transpose-store Yt[o_local][src], triple-split
#pragma unroll
      for (int i = 0; i < 2; i++) {
        int ol = (ntb + i) * 16 + lm;
#pragma unroll
        for (int r = 0; r < 4; r++) {
          int src = mt * 16 + lq * 4 + r;
          ushort a, b, c;
          split3(y[i][r], a, b, c);
          sY1[ol * PYW + src] = a;
          sY2[ol * PYW + src] = b;
          sY3[ol * PYW + src] = c;
        }
      }
      __syncthreads();
      // h += A_h @ Y_h
#pragma unroll
      for (int kf = 0; kf < 2; kf++) {
#pragma unroll
        for (int i = 0; i < 2; i++) {
          int ol = (ntb + i) * 16 + lm;
          bf16x8 y1 = *(const bf16x8*)&sY1[ol * PYW + kf * 32 + lq * 8];
          bf16x8 y2 = *(const bf16x8*)&sY2[ol * PYW + kf * 32 + lq * 8];
          bf16x8 y3 = *(const bf16x8*)&sY3[ol * PYW + kf * 32 + lq * 8];
          f32x4 c = hacc[half * 2 + i];
          MFMA6(c, Aa[kf], Ab[kf], Ac[kf], y1, y2, y3);
          hacc[half * 2 + i] = c;
        }
      }
    }
  }
}

__global__ __launch_bounds__(512, 2) void fused_gat_kernel(
    const float* __restrict__ x, const float* __restrict__ pos,
    const unsigned long long* __restrict__ mask,
    const float* __restrict__ G,           // 32 floats (both layers)
    const ushort* __restrict__ M0a, const ushort* __restrict__ M0b, const ushort* __restrict__ M0c,
    const ushort* __restrict__ M1a, const ushort* __restrict__ M1b, const ushort* __restrict__ M1c,
    const float* __restrict__ bo0, const float* __restrict__ bo1,
    float* __restrict__ h2out)             // [N][128] fp32
{
  __shared__ float  sF[64 * PFW];                    // 33.8 KB fp32 features
  __shared__ ushort sY1[64 * PYW], sY2[64 * PYW], sY3[64 * PYW];  // 27.6 KB
  __shared__ float px[64], py[64];

  int b = blockIdx.x, t = threadIdx.x;
  int wave = t >> 6, lane = t & 63, lm = lane & 15, lq = lane >> 4;
  int mt = wave & 3, ntb = (wave >> 2) * 2;

  if (t < 64) {
    px[t] = pos[(b * 64 + t) * 2];
    py[t] = pos[(b * 64 + t) * 2 + 1];
  }
  // stage X (64x64 fp32) -> sF
  {
    const float4* gx = (const float4*)(x + (size_t)b * 64 * DIN);
#pragma unroll
    for (int i = 0; i < 2; i++) {
      int idx = t + i * 512;
      int r = idx >> 4, kq = idx & 15;
      *(float4*)&sF[r * PFW + kq * 4] = gx[idx];
    }
  }
  int dst = mt * 16 + lm;
  unsigned long long m64 = mask[b * 64 + dst];
  unsigned mb0 = (unsigned)((m64 >> (8 * lq)) & 0xFF);
  unsigned mb1 = (unsigned)((m64 >> (32 + 8 * lq)) & 0xFF);
  float pd0 = pos[(b * 64 + dst) * 2], pd1 = pos[(b * 64 + dst) * 2 + 1];
  __syncthreads();

  f32x4 hacc[4];
  gat_layer<DIN>(wave, lm, lq, sF, sY1, sY2, sY3, px, py, mb0, mb1, pd0, pd1,
                 G, M0a, M0b, M0c, hacc);
  __syncthreads();   // all reads of sF (X) done before overwrite with h1
#pragma unroll
  for (int idx = 0; idx < 4; idx++) {
    int half = idx >> 1, i = idx & 1;
    int o = half * 64 + (ntb + i) * 16 + lm;
    float bv = bo0[o];
#pragma unroll
    for (int r = 0; r < 4; r++) {
      int row = mt * 16 + lq * 4 + r;
      sF[row * PFW + o] = tanhf(hacc[idx][r] + bv);
    }
  }
  __syncthreads();
  gat_layer<HID>(wave, lm, lq, sF, sY1, sY2, sY3, px, py, mb0, mb1, pd0, pd1,
                 G + 16, M1a, M1b, M1c, hacc);
  // h2 -> global fp32
#pragma unroll
  for (int idx = 0; idx < 4; idx++) {
    int half = idx >> 1, i = idx & 1;
    int o = half * 64 + (ntb + i) * 16 + lm;
    float bv = bo1[o];
#pragma unroll
    for (int r = 0; r < 4; r++) {
      int row = mt * 16 + lq * 4 + r;
      h2out[(size_t)(b * 64 + row) * HID + o] = tanhf(hacc[idx][r] + bv);
    }
  }
}

// ---------------- split-bf16 MFMA GEMM (MLP, round-3 proven) ----------------
#define PITCH 72

__global__ __launch_bounds__(256) void mgemm_kernel(
    const float* __restrict__ in, const ushort* __restrict__ Whi,
    const ushort* __restrict__ Wlo, const float* __restrict__ bias,
    float* __restrict__ out, int J, int K, int act)
{
  __shared__ ushort sAhi[64 * PITCH];
  __shared__ ushort sAlo[64 * PITCH];
  __shared__ ushort sWhi[64 * PITCH];
  __shared__ ushort sWlo[64 * PITCH];
  int t = threadIdx.x;
  int jb = blockIdx.x * 64;
  int rb = blockIdx.y * 64;
  int wave = t >> 6, lane = t & 63;
  int lm = lane & 15, lq = lane >> 4;
  int arow = wave * 16 + lm;
  f32x4 acc[4];
#pragma unroll
  for (int ct = 0; ct < 4; ct++) acc[ct] = (f32x4){0.f, 0.f, 0.f, 0.f};

  const int Kq = K >> 2, K8 = K >> 3;
  for (int k0 = 0; k0 < K; k0 += 64) {
    float4 av[4];
    const float4* gA = (const float4*)(in + (size_t)rb * K + k0);
#pragma unroll
    for (int i = 0; i < 4; i++) {
      int idx = t + i * 256;
      int r = idx >> 4, kq = idx & 15;
      av[i] = gA[(size_t)r * Kq + kq];
    }
    uint4 wh[2], wl[2];
    const uint4* gH = (const uint4*)(Whi + (size_t)jb * K + k0);
    const uint4* gL = (const uint4*)(Wlo + (size_t)jb * K + k0);
#pragma unroll
    for (int i = 0; i < 2; i++) {
      int idx = t + i * 256;
      int r = idx >> 3, kg = idx & 7;
      wh[i] = gH[(size_t)r * K8 + kg];
      wl[i] = gL[(size_t)r * K8 + kg];
    }
    __syncthreads();
#pragma unroll
    for (int i = 0; i < 4; i++) {
      int idx = t + i * 256;
      int r = idx >> 4, kq = (idx & 15) << 2;
      float4 v = av[i];
      ushort4 h, l;
      split1(v.x, h.x, l.x); split1(v.y, h.y, l.y);
      split1(v.z, h.z, l.z); split1(v.w, h.w, l.w);
      *(ushort4*)&sAhi[r * PITCH + kq] = h;
      *(ushort4*)&sAlo[r * PITCH + kq] = l;
    }
#pragma unroll
    for (int i = 0; i < 2; i++) {
      int idx = t + i * 256;
      int r = idx >> 3, kg = (idx & 7) << 3;
      *(uint4*)&sWhi[r * PITCH + kg] = wh[i];
      *(uint4*)&sWlo[r * PITCH + kg] = wl[i];
    }
    __syncthreads();
#pragma unroll
    for (int kf = 0; kf < 2; kf++) {
      int ko = kf * 32 + lq * 8;
      bf16x8 ah = *(const bf16x8*)&sAhi[arow * PITCH + ko];
      bf16x8 al = *(const bf16x8*)&sAlo[arow * PITCH + ko];
#pragma unroll
      for (int ct = 0; ct < 4; ct++) {
        bf16x8 bh = *(const bf16x8*)&sWhi[(ct * 16 + lm) * PITCH + ko];
        bf16x8 bl = *(const bf16x8*)&sWlo[(ct * 16 + lm) * PITCH + ko];
        acc[ct] = __builtin_amdgcn_mfma_f32_16x16x32_bf16(ah, bh, acc[ct], 0, 0, 0);
        acc[ct] = __builtin_amdgcn_mfma_f32_16x16x32_bf16(ah, bl, acc[ct], 0, 0, 0);
        acc[ct] = __builtin_amdgcn_mfma_f32_16x16x32_bf16(al, bh, acc[ct], 0, 0, 0);
      }
    }
  }
  int r0 = rb + wave * 16 + lq * 4;
#pragma unroll
  for (int ct = 0; ct < 4; ct++) {
    int c = jb + ct * 16 + lm;
    float bv = bias[c];
#pragma unroll
    for (int rg = 0; rg < 4; rg++) {
      float v = acc[ct][rg] + bv;
      if (act == 1) v = fmaxf(v, 0.f);
      else if (act == 2) v = tanhf(v);
      out[(size_t)(r0 + rg) * J + c] = v;
    }
  }
}

// ---------------- final tiny GEMM: out[n,0..1] = in[n,:]@W3.T + b3 ----------------
__global__ __launch_bounds__(256) void final_kernel(const float* __restrict__ in,
                                                    const float* __restrict__ W3,
                                                    const float* __restrict__ b3,
                                                    float* __restrict__ out) {
  int lane = threadIdx.x & 63;
  int nl = threadIdx.x >> 6;
  int n = blockIdx.x * 4 + nl;
  const float* row = in + (size_t)n * 256;
  float s0 = 0.f, s1 = 0.f;
#pragma unroll
  for (int tt = 0; tt < 4; tt++) {
    float xv = row[lane + 64 * tt];
    s0 += xv * W3[lane + 64 * tt];
    s1 += xv * W3[256 + lane + 64 * tt];
  }
  for (int off = 32; off >= 1; off >>= 1) {
    s0 += __shfl_xor(s0, off);
    s1 += __shfl_xor(s1, off);
  }
  if (lane == 0) {
    out[n * 2 + 0] = s0 + b3[0];
    out[n * 2 + 1] = s1 + b3[1];
  }
}

// ---------------- launch ----------------

extern "C" void kernel_launch(void* const* d_in, const int* in_sizes, int n_in,
                              void* d_out, int out_size, void* d_ws, size_t ws_size,
                              hipStream_t stream) {
  const float* x     = (const float*)d_in[0];
  const float* pos   = (const float*)d_in[1];
  const int*   ei    = (const int*)d_in[2];
  const float* l0_Wq = (const float*)d_in[3];
  const float* l0_Wk = (const float*)d_in[4];
  const float* l0_Wv = (const float*)d_in[5];
  const float* l0_Wo = (const float*)d_in[6];
  const float* l0_bo = (const float*)d_in[7];
  const float* l1_Wq = (const float*)d_in[8];
  const float* l1_Wk = (const float*)d_in[9];
  const float* l1_Wv = (const float*)d_in[10];
  const float* l1_Wo = (const float*)d_in[11];
  const float* l1_bo = (const float*)d_in[12];
  const float* W1    = (const float*)d_in[13];
  const float* b1    = (const float*)d_in[14];
  const float* W2    = (const float*)d_in[15];
  const float* b2    = (const float*)d_in[16];
  const float* W3    = (const float*)d_in[17];
  const float* b3    = (const float*)d_in[18];
  float* outp = (float*)d_out;

  int E = in_sizes[2] / 2;
  const int* srcp = ei;
  const int* dstp = ei + E;

  char* base = (char*)d_ws;
  size_t off = 0;
  auto alloc = [&](size_t bytes) -> void* {
    void* p = base + off;
    off = (off + bytes + 255) & ~(size_t)255;
    return p;
  };
  float*  G   = (float*)alloc(32 * sizeof(float));
  ushort* M0a = (ushort*)alloc((size_t)128 * 256 * 2);
  ushort* M0b = (ushort*)alloc((size_t)128 * 256 * 2);
  ushort* M0c = (ushort*)alloc((size_t)128 * 256 * 2);
  ushort* M1a = (ushort*)alloc((size_t)128 * 512 * 2);
  ushort* M1b = (ushort*)alloc((size_t)128 * 512 * 2);
  ushort* M1c = (ushort*)alloc((size_t)128 * 512 * 2);
  ushort* W1hi = (ushort*)alloc((size_t)256 * 128 * 2);
  ushort* W1lo = (ushort*)alloc((size_t)256 * 128 * 2);
  ushort* W2hi = (ushort*)alloc((size_t)256 * 256 * 2);
  ushort* W2lo = (ushort*)alloc((size_t)256 * 256 * 2);
  unsigned long long* mask = (unsigned long long*)alloc((size_t)N_NODES * 8);
  float* h2 = (float*)alloc((size_t)N_NODES * HID * sizeof(float));   // 8.4 MB
  float* m1 = (float*)alloc((size_t)N_NODES * 256 * sizeof(float));   // 16.8 MB
  float* m2 = (float*)alloc((size_t)N_NODES * 256 * sizeof(float));   // 16.8 MB

  // folded / split weights
  prep_G_kernel<<<1, 64, 0, stream>>>(l0_Wq, l0_Wk, l1_Wq, l1_Wk, G);
  prep_M_kernel<<<(128 * 256 + 255) / 256, 256, 0, stream>>>(l0_Wv, l0_Wo, M0a, M0b, M0c, DIN);
  prep_M_kernel<<<(128 * 512 + 255) / 256, 256, 0, stream>>>(l1_Wv, l1_Wo, M1a, M1b, M1c, HID);
  splitW_kernel<<<(256 * 128 + 256 * 256 + 255) / 256, 256, 0, stream>>>(
      W1, W1hi, W1lo, W2, W2hi, W2lo);

  // adjacency bitmask
  zero_kernel<<<(N_NODES + 255) / 256, 256, 0, stream>>>(mask, N_NODES);
  mask_kernel<<<(E + 255) / 256, 256, 0, stream>>>(srcp, dstp, E, mask);

  // fused 2-layer GAT -> h2
  fused_gat_kernel<<<N_NODES / 64, 512, 0, stream>>>(
      x, pos, mask, G, M0a, M0b, M0c, M1a, M1b, M1c, l0_bo, l1_bo, h2);

  // MLP
  mgemm_kernel<<<dim3(4, 256), 256, 0, stream>>>(h2, W1hi, W1lo, b1, m1, 256, 128, 1);
  mgemm_kernel<<<dim3(4, 256), 256, 0, stream>>>(m1, W2hi, W2lo, b2, m2, 256, 256, 1);
  final_kernel<<<N_NODES / 4, 256, 0, stream>>>(m2, W3, b3, outp);

  (void)n_in; (void)out_size; (void)ws_size;
}

// Round 6
// 255.659 us; speedup vs baseline: 1.2676x; 1.0127x over previous
//
#include <hip/hip_runtime.h>
#include <hip/hip_bf16.h>
#include <cstddef>
#include <math.h>

// Problem constants (from reference)
#define N_NODES 16384   // B*A
#define DIN 64
#define HID 128
#define SCALE_F 0.17677669529663687f  // 1/sqrt(32)

using bf16x8 = __attribute__((ext_vector_type(8))) short;   // 8 bf16 = 4 VGPRs
using f32x4  = __attribute__((ext_vector_type(4))) float;   // MFMA acc

__device__ __forceinline__ ushort f2b(float x) {
  __hip_bfloat16 h = __float2bfloat16(x);
  return *(ushort*)&h;
}
__device__ __forceinline__ float b2f(ushort u) {
  __hip_bfloat16 h = *(__hip_bfloat16*)&u;
  return __bfloat162float(h);
}
// fp32 -> 2-way split (hi+lo), err ~2^-18 |x|  (MLP path, proven)
__device__ __forceinline__ void split1(float x, ushort& h, ushort& l) {
  h = f2b(x);
  l = f2b(x - b2f(h));
}
// fp32 -> 3-way split (a+b+c), err ~2^-27 |x|  (GAT path, proven)
__device__ __forceinline__ void split3(float x, ushort& a, ushort& b, ushort& c) {
  a = f2b(x);
  float r1 = x - b2f(a);
  b = f2b(r1);
  c = f2b(r1 - b2f(b));
}

#define MFMA(d, A, B) d = __builtin_amdgcn_mfma_f32_16x16x32_bf16(A, B, d, 0, 0, 0)

// ---------------- small precompute ----------------

__global__ void prep_G_kernel(const float* __restrict__ Wq0, const float* __restrict__ Wk0,
                              const float* __restrict__ Wq1, const float* __restrict__ Wk1,
                              float* __restrict__ G) {
  int t = threadIdx.x;
  if (t >= 32) return;
  int l = t >> 4, h = (t >> 2) & 3, a = (t >> 1) & 1, b = t & 1;
  const float* Wq = l ? Wq1 : Wq0;
  const float* Wk = l ? Wk1 : Wk0;
  float acc = 0.f;
  for (int c = 0; c < 128; c++)
    acc += Wq[(h * 128 + c) * 2 + a] * Wk[(h * 128 + c) * 2 + b];
  G[t] = acc;
}

// Mf[o][h*D+d] = sum_c Wv[(h*128+c)*D + d] * Wo[o*512 + h*128 + c], triple-split bf16
__global__ void prep_M_kernel(const float* __restrict__ Wv, const float* __restrict__ Wo,
                              ushort* __restrict__ M1, ushort* __restrict__ M2,
                              ushort* __restrict__ M3, int D) {
  int K4 = 4 * D;
  int idx = blockIdx.x * blockDim.x + threadIdx.x;
  if (idx >= 128 * K4) return;
  int o = idx / K4, hd = idx - o * K4;
  int h = hd / D, d = hd - h * D;
  const float* wv = Wv + (size_t)(h * 128) * D + d;
  const float* wo = Wo + (size_t)o * 512 + h * 128;
  float acc = 0.f;
  for (int c = 0; c < 128; c++)
    acc += wv[(size_t)c * D] * wo[c];
  split3(acc, M1[idx], M2[idx], M3[idx]);
}

__global__ void splitW_kernel(const float* __restrict__ W1, ushort* __restrict__ W1hi,
                              ushort* __restrict__ W1lo, const float* __restrict__ W2,
                              ushort* __restrict__ W2hi, ushort* __restrict__ W2lo) {
  int i = blockIdx.x * blockDim.x + threadIdx.x;
  if (i < 256 * 128) split1(W1[i], W1hi[i], W1lo[i]);
  int j = i - 256 * 128;
  if (j >= 0 && j < 256 * 256) split1(W2[j], W2hi[j], W2lo[j]);
}

// zero adjacency mask + output accumulator (both 16384 x 8B)
__global__ void zero2_kernel(unsigned long long* __restrict__ a,
                             unsigned long long* __restrict__ b, int n) {
  int i = blockIdx.x * blockDim.x + threadIdx.x;
  if (i < n) { a[i] = 0ull; b[i] = 0ull; }
}

__global__ void mask_kernel(const int* __restrict__ src, const int* __restrict__ dst,
                            int E, unsigned long long* __restrict__ mask) {
  int e = blockIdx.x * blockDim.x + threadIdx.x;
  if (e < E) atomicOr(&mask[dst[e]], 1ull << (src[e] & 63));
}

// ---------------- fused 2-layer GAT, barrier-free schedule ----------------
// 512 threads / block, one block per 64-node graph block. Wave w owns o-tile
// [16w,16w+16). Per layer, per head: Y = F@M^T (4 src-tiles, C-regs), Y
// redistributed to B-frag layout via __shfl (no LDS), then per dst-tile:
// softmax A-frags in regs, hacc += A@Y. F lives in 3 bf16 LDS planes.
// Only 3 __syncthreads per block total.

#define PF 136   // F plane pitch (ushort): 272B rows, b128 frag reads conflict-free

template <int KD>
__device__ __forceinline__ void gat_layer(
    int wave, int lm, int lq,
    const ushort* sFa, const ushort* sFb, const ushort* sFc,
    const float* psx, const float* psy,      // [16] src pos per lane
    const float* pdx, const float* pdy,      // [4] dst pos per lane per tile
    const unsigned long long* m64,           // [4] adjacency rows
    const float* __restrict__ G,
    const ushort* __restrict__ Ma, const ushort* __restrict__ Mb,
    const ushort* __restrict__ Mc,
    f32x4 hacc[4])
{
  const int K4 = 4 * KD;
  const int o = 16 * wave + lm;
#pragma unroll
  for (int i = 0; i < 4; i++) hacc[i] = (f32x4){0.f, 0.f, 0.f, 0.f};

#pragma unroll
  for (int h = 0; h < 4; h++) {
    // ---- Y-GEMM: y[mt] = Y[src-tile mt][o], 6-term, 4 interleaved chains ----
    f32x4 y[4];
#pragma unroll
    for (int i = 0; i < 4; i++) y[i] = (f32x4){0.f, 0.f, 0.f, 0.f};
#pragma unroll
    for (int kf = 0; kf < KD / 32; kf++) {
      size_t boff = (size_t)o * K4 + h * KD + kf * 32 + lq * 8;
      bf16x8 ma = *(const bf16x8*)&Ma[boff];
      bf16x8 mb = *(const bf16x8*)&Mb[boff];
      bf16x8 mc = *(const bf16x8*)&Mc[boff];
      bf16x8 fa[4], fb[4], fc[4];
#pragma unroll
      for (int mt = 0; mt < 4; mt++) {
        int foff = (mt * 16 + lm) * PF + kf * 32 + lq * 8;
        fa[mt] = *(const bf16x8*)&sFa[foff];
        fb[mt] = *(const bf16x8*)&sFb[foff];
        fc[mt] = *(const bf16x8*)&sFc[foff];
      }
#pragma unroll
      for (int mt = 0; mt < 4; mt++) MFMA(y[mt], fa[mt], ma);
#pragma unroll
      for (int mt = 0; mt < 4; mt++) MFMA(y[mt], fa[mt], mb);
#pragma unroll
      for (int mt = 0; mt < 4; mt++) MFMA(y[mt], fb[mt], ma);
#pragma unroll
      for (int mt = 0; mt < 4; mt++) MFMA(y[mt], fa[mt], mc);
#pragma unroll
      for (int mt = 0; mt < 4; mt++) MFMA(y[mt], fc[mt], ma);
#pragma unroll
      for (int mt = 0; mt < 4; mt++) MFMA(y[mt], fb[mt], mb);
    }
    // ---- redistribute y (C-layout) -> B-frags via shuffles, then split3 ----
    // dest (lq,lm) elem j of block kb = Y[kb*32+8lq+j][o]
    //   = lane ((2lq+(j>>2))&3)*16+lm, reg y[2kb+(lq>>1)][j&3]
    bf16x8 Ya[2], Yb[2], Yc[2];
#pragma unroll
    for (int kb = 0; kb < 2; kb++) {
#pragma unroll
      for (int j = 0; j < 8; j++) {
        int sl = ((2 * lq + (j >> 2)) & 3) * 16 + lm;
        float v0 = __shfl(y[2 * kb][j & 3], sl);
        float v1 = __shfl(y[2 * kb + 1][j & 3], sl);
        float v = (lq & 2) ? v1 : v0;
        ushort ua, ub, uc;
        split3(v, ua, ub, uc);
        Ya[kb][j] = (short)ua; Yb[kb][j] = (short)ub; Yc[kb][j] = (short)uc;
      }
    }
    // ---- A@Y per dst tile: softmax A-frags in regs, 12 MFMA each ----
    float g0 = G[h * 4], g1 = G[h * 4 + 1], g2 = G[h * 4 + 2], g3 = G[h * 4 + 3];
#pragma unroll
    for (int mtd = 0; mtd < 4; mtd++) {
      float a0 = (g0 * pdx[mtd] + g2 * pdy[mtd]) * SCALE_F;
      float a1 = (g1 * pdx[mtd] + g3 * pdy[mtd]) * SCALE_F;
      unsigned mb0 = (unsigned)((m64[mtd] >> (8 * lq)) & 0xFF);
      unsigned mb1 = (unsigned)((m64[mtd] >> (32 + 8 * lq)) & 0xFF);
      float s[16];
      float mx = -1e30f;
#pragma unroll
      for (int j = 0; j < 8; j++) {
        s[j]     = a0 * psx[j]     + a1 * psy[j];
        s[8 + j] = a0 * psx[8 + j] + a1 * psy[8 + j];
        if ((mb0 >> j) & 1) mx = fmaxf(mx, s[j]);
        if ((mb1 >> j) & 1) mx = fmaxf(mx, s[8 + j]);
      }
      mx = fmaxf(mx, __shfl_xor(mx, 16));
      mx = fmaxf(mx, __shfl_xor(mx, 32));
      float e[16], sum = 0.f;
#pragma unroll
      for (int j = 0; j < 8; j++) {
        e[j]     = ((mb0 >> j) & 1) ? __expf(s[j] - mx) : 0.f;
        e[8 + j] = ((mb1 >> j) & 1) ? __expf(s[8 + j] - mx) : 0.f;
        sum += e[j] + e[8 + j];
      }
      sum += __shfl_xor(sum, 16);
      sum += __shfl_xor(sum, 32);
      float inv = 1.f / sum;
      bf16x8 Aa[2], Ab[2], Ac[2];
#pragma unroll
      for (int j = 0; j < 8; j++) {
        ushort ua, ub, uc;
        split3(e[j] * inv, ua, ub, uc);
        Aa[0][j] = (short)ua; Ab[0][j] = (short)ub; Ac[0][j] = (short)uc;
        split3(e[8 + j] * inv, ua, ub, uc);
        Aa[1][j] = (short)ua; Ab[1][j] = (short)ub; Ac[1][j] = (short)uc;
      }
#pragma unroll
      for (int kb = 0; kb < 2; kb++) {
        MFMA(hacc[mtd], Aa[kb], Ya[kb]);
        MFMA(hacc[mtd], Aa[kb], Yb[kb]);
        MFMA(hacc[mtd], Ab[kb], Ya[kb]);
        MFMA(hacc[mtd], Aa[kb], Yc[kb]);
        MFMA(hacc[mtd], Ac[kb], Ya[kb]);
        MFMA(hacc[mtd], Ab[kb], Yb[kb]);
      }
    }
  }
}

__global__ __launch_bounds__(512, 2) void fused_gat_kernel(
    const float* __restrict__ x, const float* __restrict__ pos,
    const unsigned long long* __restrict__ mask,
    const float* __restrict__ G,
    const ushort* __restrict__ M0a, const ushort* __restrict__ M0b, const ushort* __restrict__ M0c,
    const ushort* __restrict__ M1a, const ushort* __restrict__ M1b, const ushort* __restrict__ M1c,
    const float* __restrict__ bo0, const float* __restrict__ bo1,
    float* __restrict__ h2out)
{
  __shared__ ushort sFa[64 * PF], sFb[64 * PF], sFc[64 * PF];  // 52.2 KB
  __shared__ float px[64], py[64];

  int b = blockIdx.x, t = threadIdx.x;
  int wave = t >> 6, lane = t & 63, lm = lane & 15, lq = lane >> 4;

  if (t < 64) {
    px[t] = pos[(b * 64 + t) * 2];
    py[t] = pos[(b * 64 + t) * 2 + 1];
  }
  // stage X (64x64 fp32) -> triple-split planes
  {
    const float4* gx = (const float4*)(x + (size_t)b * 64 * DIN);
#pragma unroll
    for (int i = 0; i < 2; i++) {
      int idx = t + i * 512;
      float4 v = gx[idx];
      int r = idx >> 4, c = (idx & 15) * 4;
      ushort4 ua, ub, uc;
      split3(v.x, ua.x, ub.x, uc.x); split3(v.y, ua.y, ub.y, uc.y);
      split3(v.z, ua.z, ub.z, uc.z); split3(v.w, ua.w, ub.w, uc.w);
      *(ushort4*)&sFa[r * PF + c] = ua;
      *(ushort4*)&sFb[r * PF + c] = ub;
      *(ushort4*)&sFc[r * PF + c] = uc;
    }
  }
  unsigned long long m64[4];
#pragma unroll
  for (int mtd = 0; mtd < 4; mtd++) m64[mtd] = mask[b * 64 + mtd * 16 + lm];
  __syncthreads();

  // preload positions to registers
  float psx[16], psy[16], pdx[4], pdy[4];
#pragma unroll
  for (int j = 0; j < 8; j++) {
    psx[j] = px[8 * lq + j];          psy[j] = py[8 * lq + j];
    psx[8 + j] = px[32 + 8 * lq + j]; psy[8 + j] = py[32 + 8 * lq + j];
  }
#pragma unroll
  for (int mtd = 0; mtd < 4; mtd++) {
    pdx[mtd] = px[mtd * 16 + lm];
    pdy[mtd] = py[mtd * 16 + lm];
  }

  f32x4 hacc[4];
  gat_layer<DIN>(wave, lm, lq, sFa, sFb, sFc, psx, psy, pdx, pdy, m64,
                 G, M0a, M0b, M0c, hacc);
  __syncthreads();   // all layer-0 reads of X planes done
  int o = 16 * wave + lm;
  {
    float bv = bo0[o];
#pragma unroll
    for (int mtd = 0; mtd < 4; mtd++)
#pragma unroll
      for (int r = 0; r < 4; r++) {
        int dst = mtd * 16 + lq * 4 + r;
        ushort ua, ub, uc;
        split3(tanhf(hacc[mtd][r] + bv), ua, ub, uc);
        sFa[dst * PF + o] = ua;
        sFb[dst * PF + o] = ub;
        sFc[dst * PF + o] = uc;
      }
  }
  __syncthreads();
  gat_layer<HID>(wave, lm, lq, sFa, sFb, sFc, psx, psy, pdx, pdy, m64,
                 G + 16, M1a, M1b, M1c, hacc);
  {
    float bv = bo1[o];
#pragma unroll
    for (int mtd = 0; mtd < 4; mtd++)
#pragma unroll
      for (int r = 0; r < 4; r++) {
        int dst = mtd * 16 + lq * 4 + r;
        h2out[(size_t)(b * 64 + dst) * HID + o] = tanhf(hacc[mtd][r] + bv);
      }
  }
}

// ---------------- split-bf16 MFMA GEMM (W1, round-3 proven) ----------------
#define PITCH 72

__global__ __launch_bounds__(256) void mgemm_kernel(
    const float* __restrict__ in, const ushort* __restrict__ Whi,
    const ushort* __restrict__ Wlo, const float* __restrict__ bias,
    float* __restrict__ out, int J, int K, int act)
{
  __shared__ ushort sAhi[64 * PITCH];
  __shared__ ushort sAlo[64 * PITCH];
  __shared__ ushort sWhi[64 * PITCH];
  __shared__ ushort sWlo[64 * PITCH];
  int t = threadIdx.x;
  int jb = blockIdx.x * 64;
  int rb = blockIdx.y * 64;
  int wave = t >> 6, lane = t & 63;
  int lm = lane & 15, lq = lane >> 4;
  int arow = wave * 16 + lm;
  f32x4 acc[4];
#pragma unroll
  for (int ct = 0; ct < 4; ct++) acc[ct] = (f32x4){0.f, 0.f, 0.f, 0.f};

  const int Kq = K >> 2, K8 = K >> 3;
  for (int k0 = 0; k0 < K; k0 += 64) {
    float4 av[4];
    const float4* gA = (const float4*)(in + (size_t)rb * K + k0);
#pragma unroll
    for (int i = 0; i < 4; i++) {
      int idx = t + i * 256;
      int r = idx >> 4, kq = idx & 15;
      av[i] = gA[(size_t)r * Kq + kq];
    }
    uint4 wh[2], wl[2];
    const uint4* gH = (const uint4*)(Whi + (size_t)jb * K + k0);
    const uint4* gL = (const uint4*)(Wlo + (size_t)jb * K + k0);
#pragma unroll
    for (int i = 0; i < 2; i++) {
      int idx = t + i * 256;
      int r = idx >> 3, kg = idx & 7;
      wh[i] = gH[(size_t)r * K8 + kg];
      wl[i] = gL[(size_t)r * K8 + kg];
    }
    __syncthreads();
#pragma unroll
    for (int i = 0; i < 4; i++) {
      int idx = t + i * 256;
      int r = idx >> 4, kq = (idx & 15) << 2;
      float4 v = av[i];
      ushort4 h, l;
      split1(v.x, h.x, l.x); split1(v.y, h.y, l.y);
      split1(v.z, h.z, l.z); split1(v.w, h.w, l.w);
      *(ushort4*)&sAhi[r * PITCH + kq] = h;
      *(ushort4*)&sAlo[r * PITCH + kq] = l;
    }
#pragma unroll
    for (int i = 0; i < 2; i++) {
      int idx = t + i * 256;
      int r = idx >> 3, kg = (idx & 7) << 3;
      *(uint4*)&sWhi[r * PITCH + kg] = wh[i];
      *(uint4*)&sWlo[r * PITCH + kg] = wl[i];
    }
    __syncthreads();
#pragma unroll
    for (int kf = 0; kf < 2; kf++) {
      int ko = kf * 32 + lq * 8;
      bf16x8 ah = *(const bf16x8*)&sAhi[arow * PITCH + ko];
      bf16x8 al = *(const bf16x8*)&sAlo[arow * PITCH + ko];
#pragma unroll
      for (int ct = 0; ct < 4; ct++) {
        bf16x8 bh = *(const bf16x8*)&sWhi[(ct * 16 + lm) * PITCH + ko];
        bf16x8 bl = *(const bf16x8*)&sWlo[(ct * 16 + lm) * PITCH + ko];
        MFMA(acc[ct], ah, bh);
        MFMA(acc[ct], ah, bl);
        MFMA(acc[ct], al, bh);
      }
    }
  }
  int r0 = rb + wave * 16 + lq * 4;
#pragma unroll
  for (int ct = 0; ct < 4; ct++) {
    int c = jb + ct * 16 + lm;
    float bv = bias[c];
#pragma unroll
    for (int rg = 0; rg < 4; rg++) {
      float v = acc[ct][rg] + bv;
      if (act == 1) v = fmaxf(v, 0.f);
      out[(size_t)(r0 + rg) * J + c] = v;
    }
  }
}

// ---------------- W2 GEMM with fused W3 epilogue (atomic partial sums) ----------------
// m2 = relu(m1 @ W2^T + b2) computed in regs; out[r,0:2] += sum_c m2[r,c]*W3[:,c]
// (never materializes m2). J=256, K=256; grid (4, 256); block jb==0 adds b3.
__global__ __launch_bounds__(256) void mgemm_w3_kernel(
    const float* __restrict__ in, const ushort* __restrict__ Whi,
    const ushort* __restrict__ Wlo, const float* __restrict__ bias,
    const float* __restrict__ W3, const float* __restrict__ b3,
    float* __restrict__ out)
{
  const int J = 256, K = 256;
  __shared__ ushort sAhi[64 * PITCH];
  __shared__ ushort sAlo[64 * PITCH];
  __shared__ ushort sWhi[64 * PITCH];
  __shared__ ushort sWlo[64 * PITCH];
  int t = threadIdx.x;
  int jb = blockIdx.x * 64;
  int rb = blockIdx.y * 64;
  int wave = t >> 6, lane = t & 63;
  int lm = lane & 15, lq = lane >> 4;
  int arow = wave * 16 + lm;
  f32x4 acc[4];
#pragma unroll
  for (int ct = 0; ct < 4; ct++) acc[ct] = (f32x4){0.f, 0.f, 0.f, 0.f};

  const int Kq = K >> 2, K8 = K >> 3;
  for (int k0 = 0; k0 < K; k0 += 64) {
    float4 av[4];
    const float4* gA = (const float4*)(in + (size_t)rb * K + k0);
#pragma unroll
    for (int i = 0; i < 4; i++) {
      int idx = t + i * 256;
      int r = idx >> 4, kq = idx & 15;
      av[i] = gA[(size_t)r * Kq + kq];
    }
    uint4 wh[2], wl[2];
    const uint4* gH = (const uint4*)(Whi + (size_t)jb * K + k0);
    const uint4* gL = (const uint4*)(Wlo + (size_t)jb * K + k0);
#pragma unroll
    for (int i = 0; i < 2; i++) {
      int idx = t + i * 256;
      int r = idx >> 3, kg = idx & 7;
      wh[i] = gH[(size_t)r * K8 + kg];
      wl[i] = gL[(size_t)r * K8 + kg];
    }
    __syncthreads();
#pragma unroll
    for (int i = 0; i < 4; i++) {
      int idx = t + i * 256;
      int r = idx >> 4, kq = (idx & 15) << 2;
      float4 v = av[i];
      ushort h, l;
      split1(v.x, h, l); sAhi[r * PITCH + kq + 0] = h; sAlo[r * PITCH + kq + 0] = l;
      split1(v.y, h, l); sAhi[r * PITCH + kq + 1] = h; sAlo[r * PITCH + kq + 1] = l;
      split1(v.z, h, l); sAhi[r * PITCH + kq + 2] = h; sAlo[r * PITCH + kq + 2] = l;
      split1(v.w, h, l); sAhi[r * PITCH + kq + 3] = h; sAlo[r * PITCH + kq + 3] = l;
    }
#pragma unroll
    for (int i = 0; i < 2; i++) {
      int idx = t + i * 256;
      int r = idx >> 3, kg = (idx & 7) << 3;
      *(uint4*)&sWhi[r * PITCH + kg] = wh[i];
      *(uint4*)&sWlo[r * PITCH + kg] = wl[i];
    }
    __syncthreads();
#pragma unroll
    for (int kf = 0; kf < 2; kf++) {
      int ko = kf * 32 + lq * 8;
      bf16x8 ah = *(const bf16x8*)&sAhi[arow * PITCH + ko];
      bf16x8 al = *(const bf16x8*)&sAlo[arow * PITCH + ko];
#pragma unroll
      for (int ct = 0; ct < 4; ct++) {
        bf16x8 bh = *(const bf16x8*)&sWhi[(ct * 16 + lm) * PITCH + ko];
        bf16x8 bl = *(const bf16x8*)&sWlo[(ct * 16 + lm) * PITCH + ko];
        MFMA(acc[ct], ah, bh);
        MFMA(acc[ct], ah, bl);
        MFMA(acc[ct], al, bh);
      }
    }
  }
  // fused W3 epilogue
  int r0 = rb + wave * 16 + lq * 4;
  float w30[4], w31[4], bv[4];
#pragma unroll
  for (int ct = 0; ct < 4; ct++) {
    int c = jb + ct * 16 + lm;
    w30[ct] = W3[c];
    w31[ct] = W3[256 + c];
    bv[ct] = bias[c];
  }
  float bb0 = (blockIdx.x == 0) ? b3[0] : 0.f;
  float bb1 = (blockIdx.x == 0) ? b3[1] : 0.f;
#pragma unroll
  for (int rg = 0; rg < 4; rg++) {
    float s0 = 0.f, s1 = 0.f;
#pragma unroll
    for (int ct = 0; ct < 4; ct++) {
      float v = fmaxf(acc[ct][rg] + bv[ct], 0.f);
      s0 += v * w30[ct];
      s1 += v * w31[ct];
    }
    s0 += __shfl_xor(s0, 1); s0 += __shfl_xor(s0, 2); s0 += __shfl_xor(s0, 4); s0 += __shfl_xor(s0, 8);
    s1 += __shfl_xor(s1, 1); s1 += __shfl_xor(s1, 2); s1 += __shfl_xor(s1, 4); s1 += __shfl_xor(s1, 8);
    if (lm == 0) {
      int r = r0 + rg;
      atomicAdd(&out[r * 2 + 0], s0 + bb0);
      atomicAdd(&out[r * 2 + 1], s1 + bb1);
    }
  }
}

// ---------------- launch ----------------

extern "C" void kernel_launch(void* const* d_in, const int* in_sizes, int n_in,
                              void* d_out, int out_size, void* d_ws, size_t ws_size,
                              hipStream_t stream) {
  const float* x     = (const float*)d_in[0];
  const float* pos   = (const float*)d_in[1];
  const int*   ei    = (const int*)d_in[2];
  const float* l0_Wq = (const float*)d_in[3];
  const float* l0_Wk = (const float*)d_in[4];
  const float* l0_Wv = (const float*)d_in[5];
  const float* l0_Wo = (const float*)d_in[6];
  const float* l0_bo = (const float*)d_in[7];
  const float* l1_Wq = (const float*)d_in[8];
  const float* l1_Wk = (const float*)d_in[9];
  const float* l1_Wv = (const float*)d_in[10];
  const float* l1_Wo = (const float*)d_in[11];
  const float* l1_bo = (const float*)d_in[12];
  const float* W1    = (const float*)d_in[13];
  const float* b1    = (const float*)d_in[14];
  const float* W2    = (const float*)d_in[15];
  const float* b2    = (const float*)d_in[16];
  const float* W3    = (const float*)d_in[17];
  const float* b3    = (const float*)d_in[18];
  float* outp = (float*)d_out;

  int E = in_sizes[2] / 2;
  const int* srcp = ei;
  const int* dstp = ei + E;

  char* base = (char*)d_ws;
  size_t off = 0;
  auto alloc = [&](size_t bytes) -> void* {
    void* p = base + off;
    off = (off + bytes + 255) & ~(size_t)255;
    return p;
  };
  float*  G   = (float*)alloc(32 * sizeof(float));
  ushort* M0a = (ushort*)alloc((size_t)128 * 256 * 2);
  ushort* M0b = (ushort*)alloc((size_t)128 * 256 * 2);
  ushort* M0c = (ushort*)alloc((size_t)128 * 256 * 2);
  ushort* M1a = (ushort*)alloc((size_t)128 * 512 * 2);
  ushort* M1b = (ushort*)alloc((size_t)128 * 512 * 2);
  ushort* M1c = (ushort*)alloc((size_t)128 * 512 * 2);
  ushort* W1hi = (ushort*)alloc((size_t)256 * 128 * 2);
  ushort* W1lo = (ushort*)alloc((size_t)256 * 128 * 2);
  ushort* W2hi = (ushort*)alloc((size_t)256 * 256 * 2);
  ushort* W2lo = (ushort*)alloc((size_t)256 * 256 * 2);
  unsigned long long* mask = (unsigned long long*)alloc((size_t)N_NODES * 8);
  float* h2 = (float*)alloc((size_t)N_NODES * HID * sizeof(float));   // 8.4 MB
  float* m1 = (float*)alloc((size_t)N_NODES * 256 * sizeof(float));   // 16.8 MB

  // folded / split weights
  prep_G_kernel<<<1, 64, 0, stream>>>(l0_Wq, l0_Wk, l1_Wq, l1_Wk, G);
  prep_M_kernel<<<(128 * 256 + 255) / 256, 256, 0, stream>>>(l0_Wv, l0_Wo, M0a, M0b, M0c, DIN);
  prep_M_kernel<<<(128 * 512 + 255) / 256, 256, 0, stream>>>(l1_Wv, l1_Wo, M1a, M1b, M1c, HID);
  splitW_kernel<<<(256 * 128 + 256 * 256 + 255) / 256, 256, 0, stream>>>(
      W1, W1hi, W1lo, W2, W2hi, W2lo);

  // zero mask + out, build adjacency
  zero2_kernel<<<(N_NODES + 255) / 256, 256, 0, stream>>>(
      mask, (unsigned long long*)outp, N_NODES);
  mask_kernel<<<(E + 255) / 256, 256, 0, stream>>>(srcp, dstp, E, mask);

  // fused 2-layer GAT -> h2
  fused_gat_kernel<<<N_NODES / 64, 512, 0, stream>>>(
      x, pos, mask, G, M0a, M0b, M0c, M1a, M1b, M1c, l0_bo, l1_bo, h2);

  // MLP: W1 (relu) -> m1 ; W2 (relu) + W3 fused -> out
  mgemm_kernel<<<dim3(4, 256), 256, 0, stream>>>(h2, W1hi, W1lo, b1, m1, 256, 128, 1);
  mgemm_w3_kernel<<<dim3(4, 256), 256, 0, stream>>>(m1, W2hi, W2lo, b2, W3, b3, outp);

  (void)n_in; (void)out_size; (void)ws_size;
}

// Round 7
// 242.106 us; speedup vs baseline: 1.3386x; 1.0560x over previous
//
#include <hip/hip_runtime.h>
#include <hip/hip_bf16.h>
#include <cstddef>
#include <math.h>

// Problem constants (from reference)
#define N_NODES 16384   // B*A
#define DIN 64
#define HID 128
#define SCALE_F 0.17677669529663687f  // 1/sqrt(32)

using bf16x8 = __attribute__((ext_vector_type(8))) short;   // 8 bf16 = 4 VGPRs
using f32x4  = __attribute__((ext_vector_type(4))) float;   // MFMA acc

__device__ __forceinline__ ushort f2b(float x) {
  __hip_bfloat16 h = __float2bfloat16(x);
  return *(ushort*)&h;
}
__device__ __forceinline__ float b2f(ushort u) {
  __hip_bfloat16 h = *(__hip_bfloat16*)&u;
  return __bfloat162float(h);
}
// fp32 -> 2-way split (hi+lo), err ~2^-18 |x|  (MLP path, proven)
__device__ __forceinline__ void split1(float x, ushort& h, ushort& l) {
  h = f2b(x);
  l = f2b(x - b2f(h));
}
// fp32 -> 3-way split (a+b+c), err ~2^-27 |x|  (GAT path, proven)
__device__ __forceinline__ void split3(float x, ushort& a, ushort& b, ushort& c) {
  a = f2b(x);
  float r1 = x - b2f(a);
  b = f2b(r1);
  c = f2b(r1 - b2f(b));
}

#define MFMA(d, A, B) d = __builtin_amdgcn_mfma_f32_16x16x32_bf16(A, B, d, 0, 0, 0)

// ---------------- merged prep: G, M0, M1, W1/W2 splits, zero(mask,out) ----------------
// block ranges: [0] G | [1,129) M0 | [129,385) M1 | [385,769) splitW | [769,833) zero

__global__ __launch_bounds__(256) void prep_all_kernel(
    const float* __restrict__ Wq0, const float* __restrict__ Wk0,
    const float* __restrict__ Wq1, const float* __restrict__ Wk1,
    float* __restrict__ G,
    const float* __restrict__ Wv0, const float* __restrict__ Wo0,
    ushort* __restrict__ M0a, ushort* __restrict__ M0b, ushort* __restrict__ M0c,
    const float* __restrict__ Wv1, const float* __restrict__ Wo1,
    ushort* __restrict__ M1a, ushort* __restrict__ M1b, ushort* __restrict__ M1c,
    const float* __restrict__ W1, ushort* __restrict__ W1hi, ushort* __restrict__ W1lo,
    const float* __restrict__ W2, ushort* __restrict__ W2hi, ushort* __restrict__ W2lo,
    unsigned long long* __restrict__ mask, unsigned long long* __restrict__ out64)
{
  int blk = blockIdx.x, t = threadIdx.x;
  if (blk == 0) {
    if (t >= 32) return;
    int l = t >> 4, h = (t >> 2) & 3, a = (t >> 1) & 1, b = t & 1;
    const float* Wq = l ? Wq1 : Wq0;
    const float* Wk = l ? Wk1 : Wk0;
    float acc = 0.f;
    for (int c = 0; c < 128; c++)
      acc += Wq[(h * 128 + c) * 2 + a] * Wk[(h * 128 + c) * 2 + b];
    G[t] = acc;
  } else if (blk < 385) {
    // folded M = Wv^T-contract-Wo, triple-split
    int D, idx;
    const float *Wv, *Wo;
    ushort *Ma, *Mb, *Mc;
    if (blk < 129) { D = DIN; idx = (blk - 1) * 256 + t; Wv = Wv0; Wo = Wo0; Ma = M0a; Mb = M0b; Mc = M0c; }
    else           { D = HID; idx = (blk - 129) * 256 + t; Wv = Wv1; Wo = Wo1; Ma = M1a; Mb = M1b; Mc = M1c; }
    int K4 = 4 * D;
    int o = idx / K4, hd = idx - o * K4;
    int h = hd / D, d = hd - h * D;
    const float* wv = Wv + (size_t)(h * 128) * D + d;
    const float* wo = Wo + (size_t)o * 512 + h * 128;
    float acc = 0.f;
    for (int c = 0; c < 128; c++)
      acc += wv[(size_t)c * D] * wo[c];
    split3(acc, Ma[idx], Mb[idx], Mc[idx]);
  } else if (blk < 769) {
    int i = (blk - 385) * 256 + t;
    if (i < 256 * 128) split1(W1[i], W1hi[i], W1lo[i]);
    int j = i - 256 * 128;
    if (j >= 0 && j < 256 * 256) split1(W2[j], W2hi[j], W2lo[j]);
  } else {
    int i = (blk - 769) * 256 + t;
    if (i < N_NODES) { mask[i] = 0ull; out64[i] = 0ull; }
  }
}

__global__ void mask_kernel(const int* __restrict__ src, const int* __restrict__ dst,
                            int E, unsigned long long* __restrict__ mask) {
  int e = blockIdx.x * blockDim.x + threadIdx.x;
  if (e < E) atomicOr(&mask[dst[e]], 1ull << (src[e] & 63));
}

// ---------------- fused 2-layer GAT, barrier-free schedule (register-dieted) ----------------
// 512 threads / block, one block per 64-node graph block (grid = 256 = 1/CU).
// Wave w owns o-tile [16w,16w+16). Per layer, per head: Y = F@M^T (src-tiles in
// pairs to cap live regs), Y redistributed to B-frag layout via __shfl (no LDS),
// then per dst-tile: shift-invariant softmax (shift = self-loop score, always in
// mask -> no max reduction needed), A-frags in regs, hacc += A@Y.
// 3 __syncthreads per block total.

#define PF 136   // F plane pitch (ushort)

template <int KD>
__device__ __forceinline__ void gat_layer(
    int wave, int lm, int lq,
    const ushort* sFa, const ushort* sFb, const ushort* sFc,
    const float* psx, const float* psy,      // [16] src pos per lane
    const float* pdx, const float* pdy,      // [4] dst pos per lane per tile
    const unsigned long long* m64,           // [4] adjacency rows
    const float* __restrict__ G,
    const ushort* __restrict__ Ma, const ushort* __restrict__ Mb,
    const ushort* __restrict__ Mc,
    f32x4 hacc[4])
{
  const int K4 = 4 * KD;
  const int o = 16 * wave + lm;
#pragma unroll
  for (int i = 0; i < 4; i++) hacc[i] = (f32x4){0.f, 0.f, 0.f, 0.f};

#pragma unroll
  for (int h = 0; h < 4; h++) {
    // ---- Y-GEMM: y[mt] = Y[src-tile mt][o], 6-term, src-tiles in pairs ----
    f32x4 y[4];
#pragma unroll
    for (int i = 0; i < 4; i++) y[i] = (f32x4){0.f, 0.f, 0.f, 0.f};
#pragma unroll
    for (int kf = 0; kf < KD / 32; kf++) {
      size_t boff = (size_t)o * K4 + h * KD + kf * 32 + lq * 8;
      bf16x8 ma = *(const bf16x8*)&Ma[boff];
      bf16x8 mb = *(const bf16x8*)&Mb[boff];
      bf16x8 mc = *(const bf16x8*)&Mc[boff];
#pragma unroll
      for (int mp = 0; mp < 2; mp++) {   // src-tile pairs {0,1},{2,3}
        int f0 = (mp * 32 + lm) * PF + kf * 32 + lq * 8;
        int f1 = (mp * 32 + 16 + lm) * PF + kf * 32 + lq * 8;
        bf16x8 fa0 = *(const bf16x8*)&sFa[f0], fa1 = *(const bf16x8*)&sFa[f1];
        bf16x8 fb0 = *(const bf16x8*)&sFb[f0], fb1 = *(const bf16x8*)&sFb[f1];
        bf16x8 fc0 = *(const bf16x8*)&sFc[f0], fc1 = *(const bf16x8*)&sFc[f1];
        f32x4 y0 = y[mp * 2], y1 = y[mp * 2 + 1];
        MFMA(y0, fa0, ma); MFMA(y1, fa1, ma);
        MFMA(y0, fa0, mb); MFMA(y1, fa1, mb);
        MFMA(y0, fb0, ma); MFMA(y1, fb1, ma);
        MFMA(y0, fa0, mc); MFMA(y1, fa1, mc);
        MFMA(y0, fc0, ma); MFMA(y1, fc1, ma);
        MFMA(y0, fb0, mb); MFMA(y1, fb1, mb);
        y[mp * 2] = y0; y[mp * 2 + 1] = y1;
      }
    }
    // ---- redistribute y (C-layout) -> B-frags via shuffles, then split3 ----
    // dest (lq,lm) elem j of block kb = Y[kb*32+8lq+j][o]
    //   = lane ((2lq+(j>>2))&3)*16+lm, reg y[2kb+(lq>>1)][j&3]
    bf16x8 Ya[2], Yb[2], Yc[2];
#pragma unroll
    for (int kb = 0; kb < 2; kb++) {
#pragma unroll
      for (int j = 0; j < 8; j++) {
        int sl = ((2 * lq + (j >> 2)) & 3) * 16 + lm;
        float v0 = __shfl(y[2 * kb][j & 3], sl);
        float v1 = __shfl(y[2 * kb + 1][j & 3], sl);
        float v = (lq & 2) ? v1 : v0;
        ushort ua, ub, uc;
        split3(v, ua, ub, uc);
        Ya[kb][j] = (short)ua; Yb[kb][j] = (short)ub; Yc[kb][j] = (short)uc;
      }
    }
    // ---- A@Y per dst tile ----
    float g0 = G[h * 4], g1 = G[h * 4 + 1], g2 = G[h * 4 + 2], g3 = G[h * 4 + 3];
#pragma unroll
    for (int mtd = 0; mtd < 4; mtd++) {
      float a0 = (g0 * pdx[mtd] + g2 * pdy[mtd]) * SCALE_F;
      float a1 = (g1 * pdx[mtd] + g3 * pdy[mtd]) * SCALE_F;
      float sshift = a0 * pdx[mtd] + a1 * pdy[mtd];  // self-loop score (always in mask)
      unsigned mb0 = (unsigned)((m64[mtd] >> (8 * lq)) & 0xFF);
      unsigned mb1 = (unsigned)((m64[mtd] >> (32 + 8 * lq)) & 0xFF);
      float e[16];
      float sum = 0.f;
#pragma unroll
      for (int j = 0; j < 8; j++) {
        e[j]     = ((mb0 >> j) & 1) ? __expf(a0 * psx[j] + a1 * psy[j] - sshift) : 0.f;
        e[8 + j] = ((mb1 >> j) & 1) ? __expf(a0 * psx[8 + j] + a1 * psy[8 + j] - sshift) : 0.f;
        sum += e[j] + e[8 + j];
      }
      sum += __shfl_xor(sum, 16);
      sum += __shfl_xor(sum, 32);
      float inv = 1.f / sum;
      bf16x8 Aa[2], Ab[2], Ac[2];
#pragma unroll
      for (int j = 0; j < 8; j++) {
        ushort ua, ub, uc;
        split3(e[j] * inv, ua, ub, uc);
        Aa[0][j] = (short)ua; Ab[0][j] = (short)ub; Ac[0][j] = (short)uc;
        split3(e[8 + j] * inv, ua, ub, uc);
        Aa[1][j] = (short)ua; Ab[1][j] = (short)ub; Ac[1][j] = (short)uc;
      }
#pragma unroll
      for (int kb = 0; kb < 2; kb++) {
        MFMA(hacc[mtd], Aa[kb], Ya[kb]);
        MFMA(hacc[mtd], Aa[kb], Yb[kb]);
        MFMA(hacc[mtd], Ab[kb], Ya[kb]);
        MFMA(hacc[mtd], Aa[kb], Yc[kb]);
        MFMA(hacc[mtd], Ac[kb], Ya[kb]);
        MFMA(hacc[mtd], Ab[kb], Yb[kb]);
      }
    }
  }
}

__global__ __launch_bounds__(512) void fused_gat_kernel(
    const float* __restrict__ x, const float* __restrict__ pos,
    const unsigned long long* __restrict__ mask,
    const float* __restrict__ G,
    const ushort* __restrict__ M0a, const ushort* __restrict__ M0b, const ushort* __restrict__ M0c,
    const ushort* __restrict__ M1a, const ushort* __restrict__ M1b, const ushort* __restrict__ M1c,
    const float* __restrict__ bo0, const float* __restrict__ bo1,
    float* __restrict__ h2out)
{
  __shared__ ushort sFa[64 * PF], sFb[64 * PF], sFc[64 * PF];  // 52.2 KB
  __shared__ float px[64], py[64];

  int b = blockIdx.x, t = threadIdx.x;
  int wave = t >> 6, lane = t & 63, lm = lane & 15, lq = lane >> 4;

  if (t < 64) {
    px[t] = pos[(b * 64 + t) * 2];
    py[t] = pos[(b * 64 + t) * 2 + 1];
  }
  // stage X (64x64 fp32) -> triple-split planes
  {
    const float4* gx = (const float4*)(x + (size_t)b * 64 * DIN);
#pragma unroll
    for (int i = 0; i < 2; i++) {
      int idx = t + i * 512;
      float4 v = gx[idx];
      int r = idx >> 4, c = (idx & 15) * 4;
      ushort4 ua, ub, uc;
      split3(v.x, ua.x, ub.x, uc.x); split3(v.y, ua.y, ub.y, uc.y);
      split3(v.z, ua.z, ub.z, uc.z); split3(v.w, ua.w, ub.w, uc.w);
      *(ushort4*)&sFa[r * PF + c] = ua;
      *(ushort4*)&sFb[r * PF + c] = ub;
      *(ushort4*)&sFc[r * PF + c] = uc;
    }
  }
  unsigned long long m64[4];
#pragma unroll
  for (int mtd = 0; mtd < 4; mtd++) m64[mtd] = mask[b * 64 + mtd * 16 + lm];
  __syncthreads();

  // preload positions to registers
  float psx[16], psy[16], pdx[4], pdy[4];
#pragma unroll
  for (int j = 0; j < 8; j++) {
    psx[j] = px[8 * lq + j];          psy[j] = py[8 * lq + j];
    psx[8 + j] = px[32 + 8 * lq + j]; psy[8 + j] = py[32 + 8 * lq + j];
  }
#pragma unroll
  for (int mtd = 0; mtd < 4; mtd++) {
    pdx[mtd] = px[mtd * 16 + lm];
    pdy[mtd] = py[mtd * 16 + lm];
  }

  f32x4 hacc[4];
  gat_layer<DIN>(wave, lm, lq, sFa, sFb, sFc, psx, psy, pdx, pdy, m64,
                 G, M0a, M0b, M0c, hacc);
  __syncthreads();   // all layer-0 reads of X planes done
  int o = 16 * wave + lm;
  {
    float bv = bo0[o];
#pragma unroll
    for (int mtd = 0; mtd < 4; mtd++)
#pragma unroll
      for (int r = 0; r < 4; r++) {
        int dst = mtd * 16 + lq * 4 + r;
        ushort ua, ub, uc;
        split3(tanhf(hacc[mtd][r] + bv), ua, ub, uc);
        sFa[dst * PF + o] = ua;
        sFb[dst * PF + o] = ub;
        sFc[dst * PF + o] = uc;
      }
  }
  __syncthreads();
  gat_layer<HID>(wave, lm, lq, sFa, sFb, sFc, psx, psy, pdx, pdy, m64,
                 G + 16, M1a, M1b, M1c, hacc);
  {
    float bv = bo1[o];
#pragma unroll
    for (int mtd = 0; mtd < 4; mtd++)
#pragma unroll
      for (int r = 0; r < 4; r++) {
        int dst = mtd * 16 + lq * 4 + r;
        h2out[(size_t)(b * 64 + dst) * HID + o] = tanhf(hacc[mtd][r] + bv);
      }
  }
}

// ---------------- split-bf16 MFMA GEMM (W1, round-3 proven) ----------------
#define PITCH 72

__global__ __launch_bounds__(256) void mgemm_kernel(
    const float* __restrict__ in, const ushort* __restrict__ Whi,
    const ushort* __restrict__ Wlo, const float* __restrict__ bias,
    float* __restrict__ out, int J, int K, int act)
{
  __shared__ ushort sAhi[64 * PITCH];
  __shared__ ushort sAlo[64 * PITCH];
  __shared__ ushort sWhi[64 * PITCH];
  __shared__ ushort sWlo[64 * PITCH];
  int t = threadIdx.x;
  int jb = blockIdx.x * 64;
  int rb = blockIdx.y * 64;
  int wave = t >> 6, lane = t & 63;
  int lm = lane & 15, lq = lane >> 4;
  int arow = wave * 16 + lm;
  f32x4 acc[4];
#pragma unroll
  for (int ct = 0; ct < 4; ct++) acc[ct] = (f32x4){0.f, 0.f, 0.f, 0.f};

  const int Kq = K >> 2, K8 = K >> 3;
  for (int k0 = 0; k0 < K; k0 += 64) {
    float4 av[4];
    const float4* gA = (const float4*)(in + (size_t)rb * K + k0);
#pragma unroll
    for (int i = 0; i < 4; i++) {
      int idx = t + i * 256;
      int r = idx >> 4, kq = idx & 15;
      av[i] = gA[(size_t)r * Kq + kq];
    }
    uint4 wh[2], wl[2];
    const uint4* gH = (const uint4*)(Whi + (size_t)jb * K + k0);
    const uint4* gL = (const uint4*)(Wlo + (size_t)jb * K + k0);
#pragma unroll
    for (int i = 0; i < 2; i++) {
      int idx = t + i * 256;
      int r = idx >> 3, kg = idx & 7;
      wh[i] = gH[(size_t)r * K8 + kg];
      wl[i] = gL[(size_t)r * K8 + kg];
    }
    __syncthreads();
#pragma unroll
    for (int i = 0; i < 4; i++) {
      int idx = t + i * 256;
      int r = idx >> 4, kq = (idx & 15) << 2;
      float4 v = av[i];
      ushort4 h, l;
      split1(v.x, h.x, l.x); split1(v.y, h.y, l.y);
      split1(v.z, h.z, l.z); split1(v.w, h.w, l.w);
      *(ushort4*)&sAhi[r * PITCH + kq] = h;
      *(ushort4*)&sAlo[r * PITCH + kq] = l;
    }
#pragma unroll
    for (int i = 0; i < 2; i++) {
      int idx = t + i * 256;
      int r = idx >> 3, kg = (idx & 7) << 3;
      *(uint4*)&sWhi[r * PITCH + kg] = wh[i];
      *(uint4*)&sWlo[r * PITCH + kg] = wl[i];
    }
    __syncthreads();
#pragma unroll
    for (int kf = 0; kf < 2; kf++) {
      int ko = kf * 32 + lq * 8;
      bf16x8 ah = *(const bf16x8*)&sAhi[arow * PITCH + ko];
      bf16x8 al = *(const bf16x8*)&sAlo[arow * PITCH + ko];
#pragma unroll
      for (int ct = 0; ct < 4; ct++) {
        bf16x8 bh = *(const bf16x8*)&sWhi[(ct * 16 + lm) * PITCH + ko];
        bf16x8 bl = *(const bf16x8*)&sWlo[(ct * 16 + lm) * PITCH + ko];
        MFMA(acc[ct], ah, bh);
        MFMA(acc[ct], ah, bl);
        MFMA(acc[ct], al, bh);
      }
    }
  }
  int r0 = rb + wave * 16 + lq * 4;
#pragma unroll
  for (int ct = 0; ct < 4; ct++) {
    int c = jb + ct * 16 + lm;
    float bv = bias[c];
#pragma unroll
    for (int rg = 0; rg < 4; rg++) {
      float v = acc[ct][rg] + bv;
      if (act == 1) v = fmaxf(v, 0.f);
      out[(size_t)(r0 + rg) * J + c] = v;
    }
  }
}

// ---------------- W2 GEMM with fused W3 epilogue (atomic partial sums) ----------------
__global__ __launch_bounds__(256) void mgemm_w3_kernel(
    const float* __restrict__ in, const ushort* __restrict__ Whi,
    const ushort* __restrict__ Wlo, const float* __restrict__ bias,
    const float* __restrict__ W3, const float* __restrict__ b3,
    float* __restrict__ out)
{
  const int K = 256;
  __shared__ ushort sAhi[64 * PITCH];
  __shared__ ushort sAlo[64 * PITCH];
  __shared__ ushort sWhi[64 * PITCH];
  __shared__ ushort sWlo[64 * PITCH];
  int t = threadIdx.x;
  int jb = blockIdx.x * 64;
  int rb = blockIdx.y * 64;
  int wave = t >> 6, lane = t & 63;
  int lm = lane & 15, lq = lane >> 4;
  int arow = wave * 16 + lm;
  f32x4 acc[4];
#pragma unroll
  for (int ct = 0; ct < 4; ct++) acc[ct] = (f32x4){0.f, 0.f, 0.f, 0.f};

  const int Kq = K >> 2, K8 = K >> 3;
  for (int k0 = 0; k0 < K; k0 += 64) {
    float4 av[4];
    const float4* gA = (const float4*)(in + (size_t)rb * K + k0);
#pragma unroll
    for (int i = 0; i < 4; i++) {
      int idx = t + i * 256;
      int r = idx >> 4, kq = idx & 15;
      av[i] = gA[(size_t)r * Kq + kq];
    }
    uint4 wh[2], wl[2];
    const uint4* gH = (const uint4*)(Whi + (size_t)jb * K + k0);
    const uint4* gL = (const uint4*)(Wlo + (size_t)jb * K + k0);
#pragma unroll
    for (int i = 0; i < 2; i++) {
      int idx = t + i * 256;
      int r = idx >> 3, kg = idx & 7;
      wh[i] = gH[(size_t)r * K8 + kg];
      wl[i] = gL[(size_t)r * K8 + kg];
    }
    __syncthreads();
#pragma unroll
    for (int i = 0; i < 4; i++) {
      int idx = t + i * 256;
      int r = idx >> 4, kq = (idx & 15) << 2;
      float4 v = av[i];
      ushort4 h, l;
      split1(v.x, h.x, l.x); split1(v.y, h.y, l.y);
      split1(v.z, h.z, l.z); split1(v.w, h.w, l.w);
      *(ushort4*)&sAhi[r * PITCH + kq] = h;
      *(ushort4*)&sAlo[r * PITCH + kq] = l;
    }
#pragma unroll
    for (int i = 0; i < 2; i++) {
      int idx = t + i * 256;
      int r = idx >> 3, kg = (idx & 7) << 3;
      *(uint4*)&sWhi[r * PITCH + kg] = wh[i];
      *(uint4*)&sWlo[r * PITCH + kg] = wl[i];
    }
    __syncthreads();
#pragma unroll
    for (int kf = 0; kf < 2; kf++) {
      int ko = kf * 32 + lq * 8;
      bf16x8 ah = *(const bf16x8*)&sAhi[arow * PITCH + ko];
      bf16x8 al = *(const bf16x8*)&sAlo[arow * PITCH + ko];
#pragma unroll
      for (int ct = 0; ct < 4; ct++) {
        bf16x8 bh = *(const bf16x8*)&sWhi[(ct * 16 + lm) * PITCH + ko];
        bf16x8 bl = *(const bf16x8*)&sWlo[(ct * 16 + lm) * PITCH + ko];
        MFMA(acc[ct], ah, bh);
        MFMA(acc[ct], ah, bl);
        MFMA(acc[ct], al, bh);
      }
    }
  }
  // fused W3 epilogue
  int r0 = rb + wave * 16 + lq * 4;
  float w30[4], w31[4], bv[4];
#pragma unroll
  for (int ct = 0; ct < 4; ct++) {
    int c = jb + ct * 16 + lm;
    w30[ct] = W3[c];
    w31[ct] = W3[256 + c];
    bv[ct] = bias[c];
  }
  float bb0 = (blockIdx.x == 0) ? b3[0] : 0.f;
  float bb1 = (blockIdx.x == 0) ? b3[1] : 0.f;
#pragma unroll
  for (int rg = 0; rg < 4; rg++) {
    float s0 = 0.f, s1 = 0.f;
#pragma unroll
    for (int ct = 0; ct < 4; ct++) {
      float v = fmaxf(acc[ct][rg] + bv[ct], 0.f);
      s0 += v * w30[ct];
      s1 += v * w31[ct];
    }
    s0 += __shfl_xor(s0, 1); s0 += __shfl_xor(s0, 2); s0 += __shfl_xor(s0, 4); s0 += __shfl_xor(s0, 8);
    s1 += __shfl_xor(s1, 1); s1 += __shfl_xor(s1, 2); s1 += __shfl_xor(s1, 4); s1 += __shfl_xor(s1, 8);
    if (lm == 0) {
      int r = r0 + rg;
      atomicAdd(&out[r * 2 + 0], s0 + bb0);
      atomicAdd(&out[r * 2 + 1], s1 + bb1);
    }
  }
}

// ---------------- launch ----------------

extern "C" void kernel_launch(void* const* d_in, const int* in_sizes, int n_in,
                              void* d_out, int out_size, void* d_ws, size_t ws_size,
                              hipStream_t stream) {
  const float* x     = (const float*)d_in[0];
  const float* pos   = (const float*)d_in[1];
  const int*   ei    = (const int*)d_in[2];
  const float* l0_Wq = (const float*)d_in[3];
  const float* l0_Wk = (const float*)d_in[4];
  const float* l0_Wv = (const float*)d_in[5];
  const float* l0_Wo = (const float*)d_in[6];
  const float* l0_bo = (const float*)d_in[7];
  const float* l1_Wq = (const float*)d_in[8];
  const float* l1_Wk = (const float*)d_in[9];
  const float* l1_Wv = (const float*)d_in[10];
  const float* l1_Wo = (const float*)d_in[11];
  const float* l1_bo = (const float*)d_in[12];
  const float* W1    = (const float*)d_in[13];
  const float* b1    = (const float*)d_in[14];
  const float* W2    = (const float*)d_in[15];
  const float* b2    = (const float*)d_in[16];
  const float* W3    = (const float*)d_in[17];
  const float* b3    = (const float*)d_in[18];
  float* outp = (float*)d_out;

  int E = in_sizes[2] / 2;
  const int* srcp = ei;
  const int* dstp = ei + E;

  char* base = (char*)d_ws;
  size_t off = 0;
  auto alloc = [&](size_t bytes) -> void* {
    void* p = base + off;
    off = (off + bytes + 255) & ~(size_t)255;
    return p;
  };
  float*  G   = (float*)alloc(32 * sizeof(float));
  ushort* M0a = (ushort*)alloc((size_t)128 * 256 * 2);
  ushort* M0b = (ushort*)alloc((size_t)128 * 256 * 2);
  ushort* M0c = (ushort*)alloc((size_t)128 * 256 * 2);
  ushort* M1a = (ushort*)alloc((size_t)128 * 512 * 2);
  ushort* M1b = (ushort*)alloc((size_t)128 * 512 * 2);
  ushort* M1c = (ushort*)alloc((size_t)128 * 512 * 2);
  ushort* W1hi = (ushort*)alloc((size_t)256 * 128 * 2);
  ushort* W1lo = (ushort*)alloc((size_t)256 * 128 * 2);
  ushort* W2hi = (ushort*)alloc((size_t)256 * 256 * 2);
  ushort* W2lo = (ushort*)alloc((size_t)256 * 256 * 2);
  unsigned long long* mask = (unsigned long long*)alloc((size_t)N_NODES * 8);
  float* h2 = (float*)alloc((size_t)N_NODES * HID * sizeof(float));   // 8.4 MB
  float* m1 = (float*)alloc((size_t)N_NODES * 256 * sizeof(float));   // 16.8 MB

  // merged prep: G, M0, M1, W splits, zero(mask,out)
  prep_all_kernel<<<833, 256, 0, stream>>>(
      l0_Wq, l0_Wk, l1_Wq, l1_Wk, G,
      l0_Wv, l0_Wo, M0a, M0b, M0c,
      l1_Wv, l1_Wo, M1a, M1b, M1c,
      W1, W1hi, W1lo, W2, W2hi, W2lo,
      mask, (unsigned long long*)outp);
  mask_kernel<<<(E + 255) / 256, 256, 0, stream>>>(srcp, dstp, E, mask);

  // fused 2-layer GAT -> h2
  fused_gat_kernel<<<N_NODES / 64, 512, 0, stream>>>(
      x, pos, mask, G, M0a, M0b, M0c, M1a, M1b, M1c, l0_bo, l1_bo, h2);

  // MLP: W1 (relu) -> m1 ; W2 (relu) + W3 fused -> out
  mgemm_kernel<<<dim3(4, 256), 256, 0, stream>>>(h2, W1hi, W1lo, b1, m1, 256, 128, 1);
  mgemm_w3_kernel<<<dim3(4, 256), 256, 0, stream>>>(m1, W2hi, W2lo, b2, W3, b3, outp);

  (void)n_in; (void)out_size; (void)ws_size;
}

// Round 8
// 206.578 us; speedup vs baseline: 1.5688x; 1.1720x over previous
//
#include <hip/hip_runtime.h>
#include <hip/hip_bf16.h>
#include <cstddef>
#include <math.h>

// Problem constants (from reference)
#define N_NODES 16384   // B*A
#define DIN 64
#define HID 128
#define SCALE_F 0.17677669529663687f  // 1/sqrt(32)

using bf16x8 = __attribute__((ext_vector_type(8))) short;   // 8 bf16 = 4 VGPRs
using f32x4  = __attribute__((ext_vector_type(4))) float;   // MFMA acc

__device__ __forceinline__ ushort f2b(float x) {
  __hip_bfloat16 h = __float2bfloat16(x);
  return *(ushort*)&h;
}
__device__ __forceinline__ float b2f(ushort u) {
  __hip_bfloat16 h = *(__hip_bfloat16*)&u;
  return __bfloat162float(h);
}
// fp32 -> 2-way split (hi+lo), err ~2^-18 |x|  (MLP path, proven)
__device__ __forceinline__ void split1(float x, ushort& h, ushort& l) {
  h = f2b(x);
  l = f2b(x - b2f(h));
}
// fp32 -> 3-way split (a+b+c), err ~2^-27 |x|  (GAT path, proven)
__device__ __forceinline__ void split3(float x, ushort& a, ushort& b, ushort& c) {
  a = f2b(x);
  float r1 = x - b2f(a);
  b = f2b(r1);
  c = f2b(r1 - b2f(b));
}

#define MFMA(d, A, B) d = __builtin_amdgcn_mfma_f32_16x16x32_bf16(A, B, d, 0, 0, 0)

// ---------------- merged prep: G, M0, M1, W1/W2 splits, zero(mask,out) ----------------
// block ranges: [0] G | [1,129) M0 | [129,385) M1 | [385,769) splitW | [769,833) zero

__global__ __launch_bounds__(256) void prep_all_kernel(
    const float* __restrict__ Wq0, const float* __restrict__ Wk0,
    const float* __restrict__ Wq1, const float* __restrict__ Wk1,
    float* __restrict__ G,
    const float* __restrict__ Wv0, const float* __restrict__ Wo0,
    ushort* __restrict__ M0a, ushort* __restrict__ M0b, ushort* __restrict__ M0c,
    const float* __restrict__ Wv1, const float* __restrict__ Wo1,
    ushort* __restrict__ M1a, ushort* __restrict__ M1b, ushort* __restrict__ M1c,
    const float* __restrict__ W1, ushort* __restrict__ W1hi, ushort* __restrict__ W1lo,
    const float* __restrict__ W2, ushort* __restrict__ W2hi, ushort* __restrict__ W2lo,
    unsigned long long* __restrict__ mask, unsigned long long* __restrict__ out64)
{
  int blk = blockIdx.x, t = threadIdx.x;
  if (blk == 0) {
    if (t >= 32) return;
    int l = t >> 4, h = (t >> 2) & 3, a = (t >> 1) & 1, b = t & 1;
    const float* Wq = l ? Wq1 : Wq0;
    const float* Wk = l ? Wk1 : Wk0;
    float acc = 0.f;
    for (int c = 0; c < 128; c++)
      acc += Wq[(h * 128 + c) * 2 + a] * Wk[(h * 128 + c) * 2 + b];
    G[t] = acc;
  } else if (blk < 385) {
    // folded M = Wv^T-contract-Wo, triple-split
    int D, idx;
    const float *Wv, *Wo;
    ushort *Ma, *Mb, *Mc;
    if (blk < 129) { D = DIN; idx = (blk - 1) * 256 + t; Wv = Wv0; Wo = Wo0; Ma = M0a; Mb = M0b; Mc = M0c; }
    else           { D = HID; idx = (blk - 129) * 256 + t; Wv = Wv1; Wo = Wo1; Ma = M1a; Mb = M1b; Mc = M1c; }
    int K4 = 4 * D;
    int o = idx / K4, hd = idx - o * K4;
    int h = hd / D, d = hd - h * D;
    const float* wv = Wv + (size_t)(h * 128) * D + d;
    const float* wo = Wo + (size_t)o * 512 + h * 128;
    float acc = 0.f;
    for (int c = 0; c < 128; c++)
      acc += wv[(size_t)c * D] * wo[c];
    split3(acc, Ma[idx], Mb[idx], Mc[idx]);
  } else if (blk < 769) {
    int i = (blk - 385) * 256 + t;
    if (i < 256 * 128) split1(W1[i], W1hi[i], W1lo[i]);
    int j = i - 256 * 128;
    if (j >= 0 && j < 256 * 256) split1(W2[j], W2hi[j], W2lo[j]);
  } else {
    int i = (blk - 769) * 256 + t;
    if (i < N_NODES) { mask[i] = 0ull; out64[i] = 0ull; }
  }
}

__global__ void mask_kernel(const int* __restrict__ src, const int* __restrict__ dst,
                            int E, unsigned long long* __restrict__ mask) {
  int e = blockIdx.x * blockDim.x + threadIdx.x;
  if (e < E) atomicOr(&mask[dst[e]], 1ull << (src[e] & 63));
}

// ---------------- fused 2-layer GAT, barrier-free schedule ----------------
// 512 threads / block, one block per 64-node graph block (grid = 256 = 1/CU).
// Wave w owns o-tile [16w,16w+16). Per layer, per head: Y = F@M^T, Y
// redistributed to B-frag layout via __shfl (no LDS), then per dst-tile:
// shift-invariant softmax (shift = self-loop score), A-frags in regs,
// hacc += A@Y. 3 __syncthreads per block total.
// REGISTER DISCIPLINE (round-8 fix): head loop and kf loop are `unroll 1`
// so the scheduler cannot hoist global M-loads / LDS F-loads across heads
// (round 6/7 spilled ~180 MB of scratch from exactly that);
// amdgpu_waves_per_eu(2) lifts the default 128-reg allocator cap to 256.

#define PF 136   // F plane pitch (ushort)

template <int KD>
__device__ __forceinline__ void gat_layer(
    int wave, int lm, int lq,
    const ushort* sFa, const ushort* sFb, const ushort* sFc,
    const float* psx, const float* psy,      // [16] src pos per lane
    const float* pdx, const float* pdy,      // [4] dst pos per lane per tile
    const unsigned long long* m64,           // [4] adjacency rows
    const float* __restrict__ G,
    const ushort* __restrict__ Ma, const ushort* __restrict__ Mb,
    const ushort* __restrict__ Mc,
    f32x4 hacc[4])
{
  const int K4 = 4 * KD;
  const int o = 16 * wave + lm;
#pragma unroll
  for (int i = 0; i < 4; i++) hacc[i] = (f32x4){0.f, 0.f, 0.f, 0.f};

#pragma unroll 1
  for (int h = 0; h < 4; h++) {
    // ---- Y-GEMM: y[mt] = Y[src-tile mt][o], 6-term, src-tiles in pairs ----
    f32x4 y[4];
#pragma unroll
    for (int i = 0; i < 4; i++) y[i] = (f32x4){0.f, 0.f, 0.f, 0.f};
#pragma unroll 1
    for (int kf = 0; kf < KD / 32; kf++) {
      size_t boff = (size_t)o * K4 + h * KD + kf * 32 + lq * 8;
      bf16x8 ma = *(const bf16x8*)&Ma[boff];
      bf16x8 mb = *(const bf16x8*)&Mb[boff];
      bf16x8 mc = *(const bf16x8*)&Mc[boff];
#pragma unroll
      for (int mp = 0; mp < 2; mp++) {   // src-tile pairs {0,1},{2,3}
        int f0 = (mp * 32 + lm) * PF + kf * 32 + lq * 8;
        int f1 = (mp * 32 + 16 + lm) * PF + kf * 32 + lq * 8;
        bf16x8 fa0 = *(const bf16x8*)&sFa[f0], fa1 = *(const bf16x8*)&sFa[f1];
        bf16x8 fb0 = *(const bf16x8*)&sFb[f0], fb1 = *(const bf16x8*)&sFb[f1];
        bf16x8 fc0 = *(const bf16x8*)&sFc[f0], fc1 = *(const bf16x8*)&sFc[f1];
        f32x4 y0 = y[mp * 2], y1 = y[mp * 2 + 1];
        MFMA(y0, fa0, ma); MFMA(y1, fa1, ma);
        MFMA(y0, fa0, mb); MFMA(y1, fa1, mb);
        MFMA(y0, fb0, ma); MFMA(y1, fb1, ma);
        MFMA(y0, fa0, mc); MFMA(y1, fa1, mc);
        MFMA(y0, fc0, ma); MFMA(y1, fc1, ma);
        MFMA(y0, fb0, mb); MFMA(y1, fb1, mb);
        y[mp * 2] = y0; y[mp * 2 + 1] = y1;
      }
    }
    // ---- redistribute y (C-layout) -> B-frags via shuffles, then split3 ----
    // dest (lq,lm) elem j of block kb = Y[kb*32+8lq+j][o]
    //   = lane ((2lq+(j>>2))&3)*16+lm, reg y[2kb+(lq>>1)][j&3]
    bf16x8 Ya[2], Yb[2], Yc[2];
#pragma unroll
    for (int kb = 0; kb < 2; kb++) {
#pragma unroll
      for (int j = 0; j < 8; j++) {
        int sl = ((2 * lq + (j >> 2)) & 3) * 16 + lm;
        float v0 = __shfl(y[2 * kb][j & 3], sl);
        float v1 = __shfl(y[2 * kb + 1][j & 3], sl);
        float v = (lq & 2) ? v1 : v0;
        ushort ua, ub, uc;
        split3(v, ua, ub, uc);
        Ya[kb][j] = (short)ua; Yb[kb][j] = (short)ub; Yc[kb][j] = (short)uc;
      }
    }
    // ---- A@Y per dst tile ----
    float g0 = G[h * 4], g1 = G[h * 4 + 1], g2 = G[h * 4 + 2], g3 = G[h * 4 + 3];
#pragma unroll
    for (int mtd = 0; mtd < 4; mtd++) {
      float a0 = (g0 * pdx[mtd] + g2 * pdy[mtd]) * SCALE_F;
      float a1 = (g1 * pdx[mtd] + g3 * pdy[mtd]) * SCALE_F;
      float sshift = a0 * pdx[mtd] + a1 * pdy[mtd];  // self-loop score (always in mask)
      unsigned mb0 = (unsigned)((m64[mtd] >> (8 * lq)) & 0xFF);
      unsigned mb1 = (unsigned)((m64[mtd] >> (32 + 8 * lq)) & 0xFF);
      float e[16];
      float sum = 0.f;
#pragma unroll
      for (int j = 0; j < 8; j++) {
        e[j]     = ((mb0 >> j) & 1) ? __expf(a0 * psx[j] + a1 * psy[j] - sshift) : 0.f;
        e[8 + j] = ((mb1 >> j) & 1) ? __expf(a0 * psx[8 + j] + a1 * psy[8 + j] - sshift) : 0.f;
        sum += e[j] + e[8 + j];
      }
      sum += __shfl_xor(sum, 16);
      sum += __shfl_xor(sum, 32);
      float inv = 1.f / sum;
      bf16x8 Aa[2], Ab[2], Ac[2];
#pragma unroll
      for (int j = 0; j < 8; j++) {
        ushort ua, ub, uc;
        split3(e[j] * inv, ua, ub, uc);
        Aa[0][j] = (short)ua; Ab[0][j] = (short)ub; Ac[0][j] = (short)uc;
        split3(e[8 + j] * inv, ua, ub, uc);
        Aa[1][j] = (short)ua; Ab[1][j] = (short)ub; Ac[1][j] = (short)uc;
      }
#pragma unroll
      for (int kb = 0; kb < 2; kb++) {
        MFMA(hacc[mtd], Aa[kb], Ya[kb]);
        MFMA(hacc[mtd], Aa[kb], Yb[kb]);
        MFMA(hacc[mtd], Ab[kb], Ya[kb]);
        MFMA(hacc[mtd], Aa[kb], Yc[kb]);
        MFMA(hacc[mtd], Ac[kb], Ya[kb]);
        MFMA(hacc[mtd], Ab[kb], Yb[kb]);
      }
    }
  }
}

__global__ __attribute__((amdgpu_flat_work_group_size(512, 512), amdgpu_waves_per_eu(2)))
void fused_gat_kernel(
    const float* __restrict__ x, const float* __restrict__ pos,
    const unsigned long long* __restrict__ mask,
    const float* __restrict__ G,
    const ushort* __restrict__ M0a, const ushort* __restrict__ M0b, const ushort* __restrict__ M0c,
    const ushort* __restrict__ M1a, const ushort* __restrict__ M1b, const ushort* __restrict__ M1c,
    const float* __restrict__ bo0, const float* __restrict__ bo1,
    float* __restrict__ h2out)
{
  __shared__ ushort sFa[64 * PF], sFb[64 * PF], sFc[64 * PF];  // 52.2 KB
  __shared__ float px[64], py[64];

  int b = blockIdx.x, t = threadIdx.x;
  int wave = t >> 6, lane = t & 63, lm = lane & 15, lq = lane >> 4;

  if (t < 64) {
    px[t] = pos[(b * 64 + t) * 2];
    py[t] = pos[(b * 64 + t) * 2 + 1];
  }
  // stage X (64x64 fp32) -> triple-split planes
  {
    const float4* gx = (const float4*)(x + (size_t)b * 64 * DIN);
#pragma unroll
    for (int i = 0; i < 2; i++) {
      int idx = t + i * 512;
      float4 v = gx[idx];
      int r = idx >> 4, c = (idx & 15) * 4;
      ushort4 ua, ub, uc;
      split3(v.x, ua.x, ub.x, uc.x); split3(v.y, ua.y, ub.y, uc.y);
      split3(v.z, ua.z, ub.z, uc.z); split3(v.w, ua.w, ub.w, uc.w);
      *(ushort4*)&sFa[r * PF + c] = ua;
      *(ushort4*)&sFb[r * PF + c] = ub;
      *(ushort4*)&sFc[r * PF + c] = uc;
    }
  }
  unsigned long long m64[4];
#pragma unroll
  for (int mtd = 0; mtd < 4; mtd++) m64[mtd] = mask[b * 64 + mtd * 16 + lm];
  __syncthreads();

  // preload positions to registers
  float psx[16], psy[16], pdx[4], pdy[4];
#pragma unroll
  for (int j = 0; j < 8; j++) {
    psx[j] = px[8 * lq + j];          psy[j] = py[8 * lq + j];
    psx[8 + j] = px[32 + 8 * lq + j]; psy[8 + j] = py[32 + 8 * lq + j];
  }
#pragma unroll
  for (int mtd = 0; mtd < 4; mtd++) {
    pdx[mtd] = px[mtd * 16 + lm];
    pdy[mtd] = py[mtd * 16 + lm];
  }

  f32x4 hacc[4];
  gat_layer<DIN>(wave, lm, lq, sFa, sFb, sFc, psx, psy, pdx, pdy, m64,
                 G, M0a, M0b, M0c, hacc);
  __syncthreads();   // all layer-0 reads of X planes done
  int o = 16 * wave + lm;
  {
    float bv = bo0[o];
#pragma unroll
    for (int mtd = 0; mtd < 4; mtd++)
#pragma unroll
      for (int r = 0; r < 4; r++) {
        int dst = mtd * 16 + lq * 4 + r;
        ushort ua, ub, uc;
        split3(tanhf(hacc[mtd][r] + bv), ua, ub, uc);
        sFa[dst * PF + o] = ua;
        sFb[dst * PF + o] = ub;
        sFc[dst * PF + o] = uc;
      }
  }
  __syncthreads();
  gat_layer<HID>(wave, lm, lq, sFa, sFb, sFc, psx, psy, pdx, pdy, m64,
                 G + 16, M1a, M1b, M1c, hacc);
  {
    float bv = bo1[o];
#pragma unroll
    for (int mtd = 0; mtd < 4; mtd++)
#pragma unroll
      for (int r = 0; r < 4; r++) {
        int dst = mtd * 16 + lq * 4 + r;
        h2out[(size_t)(b * 64 + dst) * HID + o] = tanhf(hacc[mtd][r] + bv);
      }
  }
}

// ---------------- split-bf16 MFMA GEMM (W1, round-3 proven) ----------------
#define PITCH 72

__global__ __launch_bounds__(256) void mgemm_kernel(
    const float* __restrict__ in, const ushort* __restrict__ Whi,
    const ushort* __restrict__ Wlo, const float* __restrict__ bias,
    float* __restrict__ out, int J, int K, int act)
{
  __shared__ ushort sAhi[64 * PITCH];
  __shared__ ushort sAlo[64 * PITCH];
  __shared__ ushort sWhi[64 * PITCH];
  __shared__ ushort sWlo[64 * PITCH];
  int t = threadIdx.x;
  int jb = blockIdx.x * 64;
  int rb = blockIdx.y * 64;
  int wave = t >> 6, lane = t & 63;
  int lm = lane & 15, lq = lane >> 4;
  int arow = wave * 16 + lm;
  f32x4 acc[4];
#pragma unroll
  for (int ct = 0; ct < 4; ct++) acc[ct] = (f32x4){0.f, 0.f, 0.f, 0.f};

  const int Kq = K >> 2, K8 = K >> 3;
  for (int k0 = 0; k0 < K; k0 += 64) {
    float4 av[4];
    const float4* gA = (const float4*)(in + (size_t)rb * K + k0);
#pragma unroll
    for (int i = 0; i < 4; i++) {
      int idx = t + i * 256;
      int r = idx >> 4, kq = idx & 15;
      av[i] = gA[(size_t)r * Kq + kq];
    }
    uint4 wh[2], wl[2];
    const uint4* gH = (const uint4*)(Whi + (size_t)jb * K + k0);
    const uint4* gL = (const uint4*)(Wlo + (size_t)jb * K + k0);
#pragma unroll
    for (int i = 0; i < 2; i++) {
      int idx = t + i * 256;
      int r = idx >> 3, kg = idx & 7;
      wh[i] = gH[(size_t)r * K8 + kg];
      wl[i] = gL[(size_t)r * K8 + kg];
    }
    __syncthreads();
#pragma unroll
    for (int i = 0; i < 4; i++) {
      int idx = t + i * 256;
      int r = idx >> 4, kq = (idx & 15) << 2;
      float4 v = av[i];
      ushort4 h, l;
      split1(v.x, h.x, l.x); split1(v.y, h.y, l.y);
      split1(v.z, h.z, l.z); split1(v.w, h.w, l.w);
      *(ushort4*)&sAhi[r * PITCH + kq] = h;
      *(ushort4*)&sAlo[r * PITCH + kq] = l;
    }
#pragma unroll
    for (int i = 0; i < 2; i++) {
      int idx = t + i * 256;
      int r = idx >> 3, kg = (idx & 7) << 3;
      *(uint4*)&sWhi[r * PITCH + kg] = wh[i];
      *(uint4*)&sWlo[r * PITCH + kg] = wl[i];
    }
    __syncthreads();
#pragma unroll
    for (int kf = 0; kf < 2; kf++) {
      int ko = kf * 32 + lq * 8;
      bf16x8 ah = *(const bf16x8*)&sAhi[arow * PITCH + ko];
      bf16x8 al = *(const bf16x8*)&sAlo[arow * PITCH + ko];
#pragma unroll
      for (int ct = 0; ct < 4; ct++) {
        bf16x8 bh = *(const bf16x8*)&sWhi[(ct * 16 + lm) * PITCH + ko];
        bf16x8 bl = *(const bf16x8*)&sWlo[(ct * 16 + lm) * PITCH + ko];
        MFMA(acc[ct], ah, bh);
        MFMA(acc[ct], ah, bl);
        MFMA(acc[ct], al, bh);
      }
    }
  }
  int r0 = rb + wave * 16 + lq * 4;
#pragma unroll
  for (int ct = 0; ct < 4; ct++) {
    int c = jb + ct * 16 + lm;
    float bv = bias[c];
#pragma unroll
    for (int rg = 0; rg < 4; rg++) {
      float v = acc[ct][rg] + bv;
      if (act == 1) v = fmaxf(v, 0.f);
      out[(size_t)(r0 + rg) * J + c] = v;
    }
  }
}

// ---------------- W2 GEMM with fused W3 epilogue (atomic partial sums) ----------------
__global__ __launch_bounds__(256) void mgemm_w3_kernel(
    const float* __restrict__ in, const ushort* __restrict__ Whi,
    const ushort* __restrict__ Wlo, const float* __restrict__ bias,
    const float* __restrict__ W3, const float* __restrict__ b3,
    float* __restrict__ out)
{
  const int K = 256;
  __shared__ ushort sAhi[64 * PITCH];
  __shared__ ushort sAlo[64 * PITCH];
  __shared__ ushort sWhi[64 * PITCH];
  __shared__ ushort sWlo[64 * PITCH];
  int t = threadIdx.x;
  int jb = blockIdx.x * 64;
  int rb = blockIdx.y * 64;
  int wave = t >> 6, lane = t & 63;
  int lm = lane & 15, lq = lane >> 4;
  int arow = wave * 16 + lm;
  f32x4 acc[4];
#pragma unroll
  for (int ct = 0; ct < 4; ct++) acc[ct] = (f32x4){0.f, 0.f, 0.f, 0.f};

  const int Kq = K >> 2, K8 = K >> 3;
  for (int k0 = 0; k0 < K; k0 += 64) {
    float4 av[4];
    const float4* gA = (const float4*)(in + (size_t)rb * K + k0);
#pragma unroll
    for (int i = 0; i < 4; i++) {
      int idx = t + i * 256;
      int r = idx >> 4, kq = idx & 15;
      av[i] = gA[(size_t)r * Kq + kq];
    }
    uint4 wh[2], wl[2];
    const uint4* gH = (const uint4*)(Whi + (size_t)jb * K + k0);
    const uint4* gL = (const uint4*)(Wlo + (size_t)jb * K + k0);
#pragma unroll
    for (int i = 0; i < 2; i++) {
      int idx = t + i * 256;
      int r = idx >> 3, kg = idx & 7;
      wh[i] = gH[(size_t)r * K8 + kg];
      wl[i] = gL[(size_t)r * K8 + kg];
    }
    __syncthreads();
#pragma unroll
    for (int i = 0; i < 4; i++) {
      int idx = t + i * 256;
      int r = idx >> 4, kq = (idx & 15) << 2;
      float4 v = av[i];
      ushort4 h, l;
      split1(v.x, h.x, l.x); split1(v.y, h.y, l.y);
      split1(v.z, h.z, l.z); split1(v.w, h.w, l.w);
      *(ushort4*)&sAhi[r * PITCH + kq] = h;
      *(ushort4*)&sAlo[r * PITCH + kq] = l;
    }
#pragma unroll
    for (int i = 0; i < 2; i++) {
      int idx = t + i * 256;
      int r = idx >> 3, kg = (idx & 7) << 3;
      *(uint4*)&sWhi[r * PITCH + kg] = wh[i];
      *(uint4*)&sWlo[r * PITCH + kg] = wl[i];
    }
    __syncthreads();
#pragma unroll
    for (int kf = 0; kf < 2; kf++) {
      int ko = kf * 32 + lq * 8;
      bf16x8 ah = *(const bf16x8*)&sAhi[arow * PITCH + ko];
      bf16x8 al = *(const bf16x8*)&sAlo[arow * PITCH + ko];
#pragma unroll
      for (int ct = 0; ct < 4; ct++) {
        bf16x8 bh = *(const bf16x8*)&sWhi[(ct * 16 + lm) * PITCH + ko];
        bf16x8 bl = *(const bf16x8*)&sWlo[(ct * 16 + lm) * PITCH + ko];
        MFMA(acc[ct], ah, bh);
        MFMA(acc[ct], ah, bl);
        MFMA(acc[ct], al, bh);
      }
    }
  }
  // fused W3 epilogue
  int r0 = rb + wave * 16 + lq * 4;
  float w30[4], w31[4], bv[4];
#pragma unroll
  for (int ct = 0; ct < 4; ct++) {
    int c = jb + ct * 16 + lm;
    w30[ct] = W3[c];
    w31[ct] = W3[256 + c];
    bv[ct] = bias[c];
  }
  float bb0 = (blockIdx.x == 0) ? b3[0] : 0.f;
  float bb1 = (blockIdx.x == 0) ? b3[1] : 0.f;
#pragma unroll
  for (int rg = 0; rg < 4; rg++) {
    float s0 = 0.f, s1 = 0.f;
#pragma unroll
    for (int ct = 0; ct < 4; ct++) {
      float v = fmaxf(acc[ct][rg] + bv[ct], 0.f);
      s0 += v * w30[ct];
      s1 += v * w31[ct];
    }
    s0 += __shfl_xor(s0, 1); s0 += __shfl_xor(s0, 2); s0 += __shfl_xor(s0, 4); s0 += __shfl_xor(s0, 8);
    s1 += __shfl_xor(s1, 1); s1 += __shfl_xor(s1, 2); s1 += __shfl_xor(s1, 4); s1 += __shfl_xor(s1, 8);
    if (lm == 0) {
      int r = r0 + rg;
      atomicAdd(&out[r * 2 + 0], s0 + bb0);
      atomicAdd(&out[r * 2 + 1], s1 + bb1);
    }
  }
}

// ---------------- launch ----------------

extern "C" void kernel_launch(void* const* d_in, const int* in_sizes, int n_in,
                              void* d_out, int out_size, void* d_ws, size_t ws_size,
                              hipStream_t stream) {
  const float* x     = (const float*)d_in[0];
  const float* pos   = (const float*)d_in[1];
  const int*   ei    = (const int*)d_in[2];
  const float* l0_Wq = (const float*)d_in[3];
  const float* l0_Wk = (const float*)d_in[4];
  const float* l0_Wv = (const float*)d_in[5];
  const float* l0_Wo = (const float*)d_in[6];
  const float* l0_bo = (const float*)d_in[7];
  const float* l1_Wq = (const float*)d_in[8];
  const float* l1_Wk = (const float*)d_in[9];
  const float* l1_Wv = (const float*)d_in[10];
  const float* l1_Wo = (const float*)d_in[11];
  const float* l1_bo = (const float*)d_in[12];
  const float* W1    = (const float*)d_in[13];
  const float* b1    = (const float*)d_in[14];
  const float* W2    = (const float*)d_in[15];
  const float* b2    = (const float*)d_in[16];
  const float* W3    = (const float*)d_in[17];
  const float* b3    = (const float*)d_in[18];
  float* outp = (float*)d_out;

  int E = in_sizes[2] / 2;
  const int* srcp = ei;
  const int* dstp = ei + E;

  char* base = (char*)d_ws;
  size_t off = 0;
  auto alloc = [&](size_t bytes) -> void* {
    void* p = base + off;
    off = (off + bytes + 255) & ~(size_t)255;
    return p;
  };
  float*  G   = (float*)alloc(32 * sizeof(float));
  ushort* M0a = (ushort*)alloc((size_t)128 * 256 * 2);
  ushort* M0b = (ushort*)alloc((size_t)128 * 256 * 2);
  ushort* M0c = (ushort*)alloc((size_t)128 * 256 * 2);
  ushort* M1a = (ushort*)alloc((size_t)128 * 512 * 2);
  ushort* M1b = (ushort*)alloc((size_t)128 * 512 * 2);
  ushort* M1c = (ushort*)alloc((size_t)128 * 512 * 2);
  ushort* W1hi = (ushort*)alloc((size_t)256 * 128 * 2);
  ushort* W1lo = (ushort*)alloc((size_t)256 * 128 * 2);
  ushort* W2hi = (ushort*)alloc((size_t)256 * 256 * 2);
  ushort* W2lo = (ushort*)alloc((size_t)256 * 256 * 2);
  unsigned long long* mask = (unsigned long long*)alloc((size_t)N_NODES * 8);
  float* h2 = (float*)alloc((size_t)N_NODES * HID * sizeof(float));   // 8.4 MB
  float* m1 = (float*)alloc((size_t)N_NODES * 256 * sizeof(float));   // 16.8 MB

  // merged prep: G, M0, M1, W splits, zero(mask,out)
  prep_all_kernel<<<833, 256, 0, stream>>>(
      l0_Wq, l0_Wk, l1_Wq, l1_Wk, G,
      l0_Wv, l0_Wo, M0a, M0b, M0c,
      l1_Wv, l1_Wo, M1a, M1b, M1c,
      W1, W1hi, W1lo, W2, W2hi, W2lo,
      mask, (unsigned long long*)outp);
  mask_kernel<<<(E + 255) / 256, 256, 0, stream>>>(srcp, dstp, E, mask);

  // fused 2-layer GAT -> h2
  fused_gat_kernel<<<N_NODES / 64, 512, 0, stream>>>(
      x, pos, mask, G, M0a, M0b, M0c, M1a, M1b, M1c, l0_bo, l1_bo, h2);

  // MLP: W1 (relu) -> m1 ; W2 (relu) + W3 fused -> out
  mgemm_kernel<<<dim3(4, 256), 256, 0, stream>>>(h2, W1hi, W1lo, b1, m1, 256, 128, 1);
  mgemm_w3_kernel<<<dim3(4, 256), 256, 0, stream>>>(m1, W2hi, W2lo, b2, W3, b3, outp);

  (void)n_in; (void)out_size; (void)ws_size;
}